// Round 1
// baseline (2543.392 us; speedup 1.0000x reference)
//
#include <hip/hip_runtime.h>
#include <cstring>

#define TLEN 4096
#define DMODEL 1024
#define NHEAD 16
#define HDIM 64

// Schraudolph fast-exp, bit-exact vs reference:
//   y = A*x + B; y = (y<C || y>D) ? 0 : y; bitcast(int32(trunc(y)))
__device__ __forceinline__ float fexp_gist(float x) {
    float y = fmaf(12102203.17133801f, x, 1064986823.010288f);
    y = (y < 8388608.0f || y > 2139095040.0f) ? 0.0f : y;
    return __int_as_float((int)y);
}

// C[M][1024] = A[M][1024] @ W[1024][1024]^T (+ bias). Row-major, reduction over
// the contiguous dim of BOTH A and W ("NT" layout). 64x64 tile, 256 thr, 4x4/thr.
__global__ __launch_bounds__(256) void gemm_nt_bias(
    const float* __restrict__ A, const float* __restrict__ W,
    const float* __restrict__ bias, float* __restrict__ C)
{
    __shared__ float As[16][64];  // [k][m] transposed: compute reads are contiguous
    __shared__ float Ws[16][64];  // [k][n]
    const int m0 = blockIdx.x * 64;
    const int n0 = blockIdx.y * 64;
    const int tid = threadIdx.x;
    const int tx = tid & 15, ty = tid >> 4;
    const int srow = tid >> 2;          // staging: row 0..63
    const int sf4  = (tid & 3) * 4;     // staging: k-subcol 0/4/8/12
    float acc[4][4] = {};

    for (int k0 = 0; k0 < DMODEL; k0 += 16) {
        __syncthreads();
        float4 av = *(const float4*)&A[(size_t)(m0 + srow) * DMODEL + k0 + sf4];
        float4 wv = *(const float4*)&W[(size_t)(n0 + srow) * DMODEL + k0 + sf4];
        As[sf4+0][srow]=av.x; As[sf4+1][srow]=av.y; As[sf4+2][srow]=av.z; As[sf4+3][srow]=av.w;
        Ws[sf4+0][srow]=wv.x; Ws[sf4+1][srow]=wv.y; Ws[sf4+2][srow]=wv.z; Ws[sf4+3][srow]=wv.w;
        __syncthreads();
        #pragma unroll
        for (int kk = 0; kk < 16; ++kk) {
            float a[4], b[4];
            *(float4*)a = *(const float4*)&As[kk][ty*4];   // broadcast across tx
            *(float4*)b = *(const float4*)&Ws[kk][tx*4];   // 16 distinct b128, conflict-free
            #pragma unroll
            for (int r = 0; r < 4; ++r)
                #pragma unroll
                for (int c = 0; c < 4; ++c)
                    acc[r][c] = fmaf(a[r], b[c], acc[r][c]);
        }
    }
    float bv[4] = {0.f, 0.f, 0.f, 0.f};
    if (bias) *(float4*)bv = *(const float4*)&bias[n0 + tx*4];
    #pragma unroll
    for (int r = 0; r < 4; ++r) {
        float4 ov;
        ov.x = acc[r][0] + bv[0]; ov.y = acc[r][1] + bv[1];
        ov.z = acc[r][2] + bv[2]; ov.w = acc[r][3] + bv[3];
        *(float4*)&C[(size_t)(m0 + ty*4 + r) * DMODEL + n0 + tx*4] = ov;
    }
}

// Fused attention for one (head, 64 q-rows) block. Two passes over K/V so the
// gist-exp sees exactly (score - global_row_max), matching reference semantics.
__global__ __launch_bounds__(256) void attn_fused(
    const float* __restrict__ q, const float* __restrict__ kmat,
    const float* __restrict__ vmat, float* __restrict__ o, float scaling)
{
    __shared__ float Qs[64][64];   // [d][m] transposed
    __shared__ float Ks[64][64];   // [d][n] transposed
    __shared__ float Vs[64][64];   // [j][d] natural
    __shared__ float Es[64][68];   // [j][m], padded row 68 floats (272B, 16B-aligned)
    __shared__ float Ms[64];       // per-row global max (scaled)

    const int t0 = blockIdx.x * 64;
    const int hc = blockIdx.y * HDIM;
    const int tid = threadIdx.x;
    const int tx = tid & 15, ty = tid >> 4;
    const int srow = tid >> 2;

    // stage Q transposed: Qs[d][m] = q[t0+m][hc+d]
    #pragma unroll
    for (int rep = 0; rep < 4; ++rep) {
        int d0 = ((tid & 3) + rep * 4) * 4;
        float4 t = *(const float4*)&q[(size_t)(t0 + srow) * DMODEL + hc + d0];
        Qs[d0+0][srow]=t.x; Qs[d0+1][srow]=t.y; Qs[d0+2][srow]=t.z; Qs[d0+3][srow]=t.w;
    }

    // ---- pass 1: per-row max of raw dot products (scaling applied after:
    //      round(c*x) is monotone in x for c>0, so max commutes with the mul)
    float rmax[4] = {-3.402823466e38f, -3.402823466e38f, -3.402823466e38f, -3.402823466e38f};
    for (int j0 = 0; j0 < TLEN; j0 += 64) {
        __syncthreads();
        #pragma unroll
        for (int rep = 0; rep < 4; ++rep) {
            int d0 = ((tid & 3) + rep * 4) * 4;
            float4 t = *(const float4*)&kmat[(size_t)(j0 + srow) * DMODEL + hc + d0];
            Ks[d0+0][srow]=t.x; Ks[d0+1][srow]=t.y; Ks[d0+2][srow]=t.z; Ks[d0+3][srow]=t.w;
        }
        __syncthreads();
        float s[4][4] = {};
        #pragma unroll
        for (int d = 0; d < 64; ++d) {
            float a[4], b[4];
            *(float4*)a = *(const float4*)&Qs[d][ty*4];
            *(float4*)b = *(const float4*)&Ks[d][tx*4];
            #pragma unroll
            for (int r = 0; r < 4; ++r)
                #pragma unroll
                for (int c = 0; c < 4; ++c)
                    s[r][c] = fmaf(a[r], b[c], s[r][c]);
        }
        #pragma unroll
        for (int r = 0; r < 4; ++r)
            #pragma unroll
            for (int c = 0; c < 4; ++c)
                rmax[r] = fmaxf(rmax[r], s[r][c]);
    }
    #pragma unroll
    for (int off = 1; off < 16; off <<= 1) {
        #pragma unroll
        for (int r = 0; r < 4; ++r)
            rmax[r] = fmaxf(rmax[r], __shfl_xor(rmax[r], off, 64));
    }
    if (tx == 0) {
        #pragma unroll
        for (int r = 0; r < 4; ++r) Ms[ty*4+r] = rmax[r] * scaling;
    }
    __syncthreads();
    float mr[4];
    #pragma unroll
    for (int r = 0; r < 4; ++r) mr[r] = Ms[ty*4+r];

    // ---- pass 2: e = gist(score - m); accumulate sum(e) and e @ V
    float oacc[4][4] = {};
    float se[4] = {0.f, 0.f, 0.f, 0.f};
    for (int j0 = 0; j0 < TLEN; j0 += 64) {
        __syncthreads();
        #pragma unroll
        for (int rep = 0; rep < 4; ++rep) {
            int d0 = ((tid & 3) + rep * 4) * 4;
            float4 t = *(const float4*)&kmat[(size_t)(j0 + srow) * DMODEL + hc + d0];
            Ks[d0+0][srow]=t.x; Ks[d0+1][srow]=t.y; Ks[d0+2][srow]=t.z; Ks[d0+3][srow]=t.w;
        }
        #pragma unroll
        for (int rep = 0; rep < 4; ++rep) {
            int vrow = (tid >> 4) + rep * 16;
            float4 t = *(const float4*)&vmat[(size_t)(j0 + vrow) * DMODEL + hc + (tid & 15) * 4];
            *(float4*)&Vs[vrow][(tid & 15) * 4] = t;
        }
        __syncthreads();
        float s[4][4] = {};
        #pragma unroll
        for (int d = 0; d < 64; ++d) {
            float a[4], b[4];
            *(float4*)a = *(const float4*)&Qs[d][ty*4];
            *(float4*)b = *(const float4*)&Ks[d][tx*4];
            #pragma unroll
            for (int r = 0; r < 4; ++r)
                #pragma unroll
                for (int c = 0; c < 4; ++c)
                    s[r][c] = fmaf(a[r], b[c], s[r][c]);
        }
        #pragma unroll
        for (int r = 0; r < 4; ++r)
            #pragma unroll
            for (int c = 0; c < 4; ++c) {
                float sc = s[r][c] * scaling;          // matches ref: mul then sub
                float e = fexp_gist(sc - mr[r]);
                se[r] += e;
                Es[tx*4+c][ty*4+r] = e;                // [j][m]
            }
        __syncthreads();
        #pragma unroll
        for (int j = 0; j < 64; ++j) {
            float a[4], b[4];
            *(float4*)a = *(const float4*)&Es[j][ty*4]; // broadcast across tx
            *(float4*)b = *(const float4*)&Vs[j][tx*4]; // contiguous
            #pragma unroll
            for (int r = 0; r < 4; ++r)
                #pragma unroll
                for (int c = 0; c < 4; ++c)
                    oacc[r][c] = fmaf(a[r], b[c], oacc[r][c]);
        }
    }
    #pragma unroll
    for (int off = 1; off < 16; off <<= 1) {
        #pragma unroll
        for (int r = 0; r < 4; ++r)
            se[r] += __shfl_xor(se[r], off, 64);
    }
    #pragma unroll
    for (int r = 0; r < 4; ++r) {
        float4 ov;
        ov.x = oacc[r][0] / se[r]; ov.y = oacc[r][1] / se[r];
        ov.z = oacc[r][2] / se[r]; ov.w = oacc[r][3] / se[r];
        *(float4*)&o[(size_t)(t0 + ty*4 + r) * DMODEL + hc + tx*4] = ov;
    }
}

extern "C" void kernel_launch(void* const* d_in, const int* in_sizes, int n_in,
                              void* d_out, int out_size, void* d_ws, size_t ws_size,
                              hipStream_t stream)
{
    const float* x  = (const float*)d_in[0];
    const float* Wq = (const float*)d_in[1];
    const float* bq = (const float*)d_in[2];
    const float* Wk = (const float*)d_in[3];
    const float* bk = (const float*)d_in[4];
    const float* Wv = (const float*)d_in[5];
    const float* bv = (const float*)d_in[6];
    const float* Wo = (const float*)d_in[7];
    float* out = (float*)d_out;

    float* qbuf = (float*)d_ws;                       // [T][1024]
    float* kbuf = qbuf + (size_t)TLEN * DMODEL;       // [T][1024]
    float* vbuf = kbuf + (size_t)TLEN * DMODEL;       // [T][1024]
    float* obuf = vbuf + (size_t)TLEN * DMODEL;       // [T][1024]
    // total ws use: 64 MB

    // Quake fast inverse sqrt of HEAD_DIM, bit-exact vs reference (host-side)
    float hx = (float)HDIM;
    int bi; memcpy(&bi, &hx, 4);
    bi = (int)(0x5F3759DFLL - ((long long)bi >> 1));
    float yy; memcpy(&yy, &bi, 4);
    float scaling = yy * (1.5f - 0.5f * hx * yy * yy);

    dim3 blk(256);
    dim3 ggemm(TLEN / 64, DMODEL / 64);
    gemm_nt_bias<<<ggemm, blk, 0, stream>>>(x, Wq, bq, qbuf);
    gemm_nt_bias<<<ggemm, blk, 0, stream>>>(x, Wk, bk, kbuf);
    gemm_nt_bias<<<ggemm, blk, 0, stream>>>(x, Wv, bv, vbuf);
    attn_fused<<<dim3(TLEN / 64, NHEAD), blk, 0, stream>>>(qbuf, kbuf, vbuf, obuf, scaling);
    gemm_nt_bias<<<ggemm, blk, 0, stream>>>(obuf, Wo, nullptr, out);
}

// Round 2
// 619.194 us; speedup vs baseline: 4.1076x; 4.1076x over previous
//
#include <hip/hip_runtime.h>
#include <cstring>

typedef unsigned short u16;
typedef unsigned int   u32;
typedef __attribute__((ext_vector_type(8))) short bfrag;   // 8 bf16 = 4 VGPR
typedef __attribute__((ext_vector_type(4))) float ffrag;   // 4 f32 acc

#define TLEN 4096
#define DM   1024
#define NHEAD 16
#define HD    64

// round-to-nearest-even fp32 -> bf16 (bits)
__device__ __forceinline__ u16 f2bf(float f) {
    u32 u = __float_as_uint(f);
    u32 r = (u + 0x7FFFu + ((u >> 16) & 1u)) >> 16;
    return (u16)r;
}
__device__ __forceinline__ float bf2f(u16 h) { return __uint_as_float(((u32)h) << 16); }

// Schraudolph fast-exp, bit-exact vs reference
__device__ __forceinline__ float fexp_gist(float x) {
    float y = fmaf(12102203.17133801f, x, 1064986823.010288f);
    y = (y < 8388608.0f || y > 2139095040.0f) ? 0.0f : y;
    return __int_as_float((int)y);
}

#define GLD16(gsrc, ldst) \
  __builtin_amdgcn_global_load_lds((const __attribute__((address_space(1))) u32*)(gsrc), \
                                   (__attribute__((address_space(3))) u32*)(ldst), 16, 0, 0)

// ---------------- split fp32 -> (hi, lo) bf16 ----------------
__global__ __launch_bounds__(256) void split_k(const float* __restrict__ a,
                                               u16* __restrict__ hi, u16* __restrict__ lo) {
    int i = (blockIdx.x * 256 + threadIdx.x) * 4;
    float4 v = *(const float4*)&a[i];
    u16 h0 = f2bf(v.x), h1 = f2bf(v.y), h2 = f2bf(v.z), h3 = f2bf(v.w);
    ushort4 hv; hv.x = h0; hv.y = h1; hv.z = h2; hv.w = h3;
    ushort4 lv;
    lv.x = f2bf(v.x - bf2f(h0)); lv.y = f2bf(v.y - bf2f(h1));
    lv.z = f2bf(v.z - bf2f(h2)); lv.w = f2bf(v.w - bf2f(h3));
    *(ushort4*)&hi[i] = hv;
    *(ushort4*)&lo[i] = lv;
}

// ---------------- bf16x3 GEMM: C[M][N] = A[M][K=1024] * W[N][K]^T (+bias) ----------------
// 128x128 tile, BK=32, 256 thr (4 waves, each 64x64 = 4x4 MFMA frags).
// LDS slot-swizzled (slot ^= (row>>1)&3) so frag ds_read_b128 are conflict-free;
// global_load_lds sources are pre-swizzled to compensate (linear LDS dest).
__global__ __launch_bounds__(256) void gemm_bx3(
    const u16* __restrict__ Ah, const u16* __restrict__ Al,
    const u16* __restrict__ Wh, const u16* __restrict__ Wl,
    const float* __restrict__ bias,
    float* __restrict__ Cf, u16* __restrict__ Chi, u16* __restrict__ Clo,
    int trans, int M, int N)
{
    __shared__ u16 Ash[2][4096];   // [hi/lo][128 rows x 32 k]
    __shared__ u16 Wsh[2][4096];
    const int tid = threadIdx.x;
    const int w = tid >> 6, lane = tid & 63, lr = lane & 15, lg = lane >> 4;
    const int wm = w >> 1, wn = w & 1;
    const int m0 = blockIdx.x * 128, n0 = blockIdx.y * 128;

    ffrag acc[4][4];
    #pragma unroll
    for (int i = 0; i < 4; ++i)
        #pragma unroll
        for (int j = 0; j < 4; ++j) acc[i][j] = (ffrag)(0.0f);

    #pragma unroll 1
    for (int k0 = 0; k0 < DM; k0 += 32) {
        __syncthreads();
        #pragma unroll
        for (int i = 0; i < 2; ++i) {
            int o   = (i * 256 + tid) * 16;        // byte offset in 8KB tile
            int row = o >> 6;                      // 64B rows
            int sl  = ((o >> 4) & 3) ^ ((row >> 1) & 3);
            const size_t ga = (size_t)(m0 + row) * DM + k0 + sl * 8;
            const size_t gw = (size_t)(n0 + row) * DM + k0 + sl * 8;
            GLD16(Ah + ga, ((char*)&Ash[0][0]) + o);
            GLD16(Al + ga, ((char*)&Ash[1][0]) + o);
            GLD16(Wh + gw, ((char*)&Wsh[0][0]) + o);
            GLD16(Wl + gw, ((char*)&Wsh[1][0]) + o);
        }
        __syncthreads();
        bfrag ah[4], al[4], bh[4], bl[4];
        #pragma unroll
        for (int f = 0; f < 4; ++f) {
            int ra = wm * 64 + f * 16 + lr;
            int oa = ra * 64 + ((lg ^ ((ra >> 1) & 3)) * 16);
            ah[f] = *(const bfrag*)(((const char*)&Ash[0][0]) + oa);
            al[f] = *(const bfrag*)(((const char*)&Ash[1][0]) + oa);
            int rb = wn * 64 + f * 16 + lr;
            int ob = rb * 64 + ((lg ^ ((rb >> 1) & 3)) * 16);
            bh[f] = *(const bfrag*)(((const char*)&Wsh[0][0]) + ob);
            bl[f] = *(const bfrag*)(((const char*)&Wsh[1][0]) + ob);
        }
        #pragma unroll
        for (int mf = 0; mf < 4; ++mf)
            #pragma unroll
            for (int nf = 0; nf < 4; ++nf) {
                acc[mf][nf] = __builtin_amdgcn_mfma_f32_16x16x32_bf16(ah[mf], bh[nf], acc[mf][nf], 0, 0, 0);
                acc[mf][nf] = __builtin_amdgcn_mfma_f32_16x16x32_bf16(ah[mf], bl[nf], acc[mf][nf], 0, 0, 0);
                acc[mf][nf] = __builtin_amdgcn_mfma_f32_16x16x32_bf16(al[mf], bh[nf], acc[mf][nf], 0, 0, 0);
            }
    }

    float bv[4] = {0.f, 0.f, 0.f, 0.f};
    if (bias) {
        #pragma unroll
        for (int nf = 0; nf < 4; ++nf) bv[nf] = bias[n0 + wn * 64 + nf * 16 + lr];
    }
    #pragma unroll
    for (int mf = 0; mf < 4; ++mf)
        #pragma unroll
        for (int nf = 0; nf < 4; ++nf)
            #pragma unroll
            for (int r = 0; r < 4; ++r) {
                int row = m0 + wm * 64 + mf * 16 + lg * 4 + r;
                int col = n0 + wn * 64 + nf * 16 + lr;
                float v = acc[mf][nf][r] + bv[nf];
                if (Cf) Cf[(size_t)row * N + col] = v;
                if (Chi) {
                    u16 h = f2bf(v), l = f2bf(v - bf2f(h));
                    size_t idx = trans ? ((size_t)col * M + row) : ((size_t)row * N + col);
                    Chi[idx] = h; Clo[idx] = l;
                }
            }
}

// ---------------- fused attention, bf16x3 MFMA ----------------
// Block = 4 waves x 64 lanes; wave w owns q-rows [t0+16w, t0+16w+16).
// Pass 1: global row max via pure-bf16 QK (error cancels to 1st order in softmax).
// Pass 2: QK bf16x3 -> gist-exp -> e split hi/lo through LDS -> PV bf16x3.
__global__ __launch_bounds__(256, 2) void attn_mfma(
    const u16* __restrict__ qh_, const u16* __restrict__ ql_,
    const u16* __restrict__ kh_, const u16* __restrict__ kl_,
    const u16* __restrict__ vth_, const u16* __restrict__ vtl_,   // [DM][TLEN] transposed
    u16* __restrict__ oh_, u16* __restrict__ ol_, float scaling)
{
    __shared__ u16 Kh[4096], Kl[4096];     // [64 keys][64 d], swizzled (slot ^= row&7)
    __shared__ u16 Vh[4096], Vl[4096];     // [64 d][64 keys], swizzled
    __shared__ u16 Esh[4][16][72], Esl[4][16][72];  // per-wave e tiles, stride 144B

    const int tid = threadIdx.x;
    const int w = tid >> 6, lane = tid & 63, lr = lane & 15, lg = lane >> 4;
    const int t0 = blockIdx.x * 64, hc = blockIdx.y * HD;

    // Q fragments (A-side: row = lr, k = kf*32 + lg*8)
    bfrag qh[2], ql[2];
    {
        const size_t qoff = (size_t)(t0 + w * 16 + lr) * DM + hc;
        #pragma unroll
        for (int kf = 0; kf < 2; ++kf) {
            qh[kf] = *(const bfrag*)&qh_[qoff + kf * 32 + lg * 8];
            ql[kf] = *(const bfrag*)&ql_[qoff + kf * 32 + lg * 8];
        }
    }

    // ---- pass 1: global row max (pure bf16 QK) ----
    float rmax[4] = {-3.402823466e38f, -3.402823466e38f, -3.402823466e38f, -3.402823466e38f};
    #pragma unroll 1
    for (int j0 = 0; j0 < TLEN; j0 += 64) {
        __syncthreads();
        #pragma unroll
        for (int i = 0; i < 2; ++i) {
            int o   = (i * 256 + tid) * 16;
            int row = o >> 7;                      // 128B rows
            int sl  = ((o >> 4) & 7) ^ (row & 7);
            GLD16(kh_ + (size_t)(j0 + row) * DM + hc + sl * 8, ((char*)Kh) + o);
        }
        __syncthreads();
        ffrag s[4];
        #pragma unroll
        for (int nf = 0; nf < 4; ++nf) s[nf] = (ffrag)(0.0f);
        #pragma unroll
        for (int nf = 0; nf < 4; ++nf)
            #pragma unroll
            for (int kf = 0; kf < 2; ++kf) {
                int kr = nf * 16 + lr;
                int ob = kr * 128 + (((kf * 4 + lg) ^ (kr & 7)) * 16);
                bfrag b = *(const bfrag*)(((const char*)Kh) + ob);
                s[nf] = __builtin_amdgcn_mfma_f32_16x16x32_bf16(qh[kf], b, s[nf], 0, 0, 0);
            }
        #pragma unroll
        for (int nf = 0; nf < 4; ++nf)
            #pragma unroll
            for (int r = 0; r < 4; ++r) rmax[r] = fmaxf(rmax[r], s[nf][r]);
    }
    #pragma unroll
    for (int off = 1; off < 16; off <<= 1)
        #pragma unroll
        for (int r = 0; r < 4; ++r) rmax[r] = fmaxf(rmax[r], __shfl_xor(rmax[r], off, 64));
    float mr[4];
    #pragma unroll
    for (int r = 0; r < 4; ++r) mr[r] = rmax[r] * scaling;

    // ---- pass 2: e = gist(s*scale - m); O += e*V; se += e ----
    ffrag oacc[4];
    #pragma unroll
    for (int nf = 0; nf < 4; ++nf) oacc[nf] = (ffrag)(0.0f);
    float se[4] = {0.f, 0.f, 0.f, 0.f};

    #pragma unroll 1
    for (int j0 = 0; j0 < TLEN; j0 += 64) {
        __syncthreads();
        #pragma unroll
        for (int i = 0; i < 2; ++i) {
            int o   = (i * 256 + tid) * 16;
            int row = o >> 7;
            int sl  = ((o >> 4) & 7) ^ (row & 7);
            const size_t koff = (size_t)(j0 + row) * DM + hc + sl * 8;
            const size_t voff = (size_t)(hc + row) * TLEN + j0 + sl * 8;
            GLD16(kh_ + koff, ((char*)Kh) + o);
            GLD16(kl_ + koff, ((char*)Kl) + o);
            GLD16(vth_ + voff, ((char*)Vh) + o);
            GLD16(vtl_ + voff, ((char*)Vl) + o);
        }
        __syncthreads();

        ffrag s[4];
        #pragma unroll
        for (int nf = 0; nf < 4; ++nf) s[nf] = (ffrag)(0.0f);
        #pragma unroll
        for (int nf = 0; nf < 4; ++nf)
            #pragma unroll
            for (int kf = 0; kf < 2; ++kf) {
                int kr = nf * 16 + lr;
                int ob = kr * 128 + (((kf * 4 + lg) ^ (kr & 7)) * 16);
                bfrag bh = *(const bfrag*)(((const char*)Kh) + ob);
                bfrag bl = *(const bfrag*)(((const char*)Kl) + ob);
                s[nf] = __builtin_amdgcn_mfma_f32_16x16x32_bf16(qh[kf], bh, s[nf], 0, 0, 0);
                s[nf] = __builtin_amdgcn_mfma_f32_16x16x32_bf16(qh[kf], bl, s[nf], 0, 0, 0);
                s[nf] = __builtin_amdgcn_mfma_f32_16x16x32_bf16(ql[kf], bh, s[nf], 0, 0, 0);
            }

        #pragma unroll
        for (int nf = 0; nf < 4; ++nf)
            #pragma unroll
            for (int r = 0; r < 4; ++r) {
                float e = fexp_gist(s[nf][r] * scaling - mr[r]);
                se[r] += e;
                u16 eh = f2bf(e), el = f2bf(e - bf2f(eh));
                Esh[w][lg * 4 + r][nf * 16 + lr] = eh;
                Esl[w][lg * 4 + r][nf * 16 + lr] = el;
            }
        // same-wave LDS write->read: in-order, no barrier needed

        #pragma unroll
        for (int kf = 0; kf < 2; ++kf) {
            bfrag ph = *(const bfrag*)&Esh[w][lr][kf * 32 + lg * 8];
            bfrag pl = *(const bfrag*)&Esl[w][lr][kf * 32 + lg * 8];
            #pragma unroll
            for (int nf = 0; nf < 4; ++nf) {
                int vr = nf * 16 + lr;
                int ov = vr * 128 + (((kf * 4 + lg) ^ (vr & 7)) * 16);
                bfrag vh = *(const bfrag*)(((const char*)Vh) + ov);
                bfrag vl = *(const bfrag*)(((const char*)Vl) + ov);
                oacc[nf] = __builtin_amdgcn_mfma_f32_16x16x32_bf16(ph, vh, oacc[nf], 0, 0, 0);
                oacc[nf] = __builtin_amdgcn_mfma_f32_16x16x32_bf16(ph, vl, oacc[nf], 0, 0, 0);
                oacc[nf] = __builtin_amdgcn_mfma_f32_16x16x32_bf16(pl, vh, oacc[nf], 0, 0, 0);
            }
        }
    }

    #pragma unroll
    for (int off = 1; off < 16; off <<= 1)
        #pragma unroll
        for (int r = 0; r < 4; ++r) se[r] += __shfl_xor(se[r], off, 64);

    #pragma unroll
    for (int nf = 0; nf < 4; ++nf)
        #pragma unroll
        for (int r = 0; r < 4; ++r) {
            int row = t0 + w * 16 + lg * 4 + r;
            int col = hc + nf * 16 + lr;
            float v = oacc[nf][r] / se[r];
            u16 h = f2bf(v), l = f2bf(v - bf2f(h));
            oh_[(size_t)row * DM + col] = h;
            ol_[(size_t)row * DM + col] = l;
        }
}

extern "C" void kernel_launch(void* const* d_in, const int* in_sizes, int n_in,
                              void* d_out, int out_size, void* d_ws, size_t ws_size,
                              hipStream_t stream)
{
    const float* x  = (const float*)d_in[0];
    const float* Wq = (const float*)d_in[1];
    const float* bq = (const float*)d_in[2];
    const float* Wk = (const float*)d_in[3];
    const float* bk = (const float*)d_in[4];
    const float* Wv = (const float*)d_in[5];
    const float* bv = (const float*)d_in[6];
    const float* Wo = (const float*)d_in[7];
    float* out = (float*)d_out;

    // workspace layout (bf16 halves), 80 MB total
    u16* p = (u16*)d_ws;
    u16* xh  = p; p += (size_t)TLEN * DM;
    u16* xl  = p; p += (size_t)TLEN * DM;
    u16* wqh = p; p += (size_t)DM * DM;  u16* wql = p; p += (size_t)DM * DM;
    u16* wkh = p; p += (size_t)DM * DM;  u16* wkl = p; p += (size_t)DM * DM;
    u16* wvh = p; p += (size_t)DM * DM;  u16* wvl = p; p += (size_t)DM * DM;
    u16* woh = p; p += (size_t)DM * DM;  u16* wol = p; p += (size_t)DM * DM;
    u16* qh  = p; p += (size_t)TLEN * DM;  u16* ql  = p; p += (size_t)TLEN * DM;
    u16* kh  = p; p += (size_t)TLEN * DM;  u16* kl  = p; p += (size_t)TLEN * DM;
    u16* vth = p; p += (size_t)TLEN * DM;  u16* vtl = p; p += (size_t)TLEN * DM;
    u16* oh = xh;  u16* ol = xl;   // x fully consumed by projections before attn writes o

    // Quake fast-rsqrt(HEAD_DIM), bit-exact vs reference (host-side)
    float hx = (float)HD;
    int bi; memcpy(&bi, &hx, 4);
    bi = (int)(0x5F3759DFLL - ((long long)bi >> 1));
    float yy; memcpy(&yy, &bi, 4);
    float scaling = yy * (1.5f - 0.5f * hx * yy * yy);

    split_k<<<4096, 256, 0, stream>>>(x,  xh,  xl);
    split_k<<<1024, 256, 0, stream>>>(Wq, wqh, wql);
    split_k<<<1024, 256, 0, stream>>>(Wk, wkh, wkl);
    split_k<<<1024, 256, 0, stream>>>(Wv, wvh, wvl);
    split_k<<<1024, 256, 0, stream>>>(Wo, woh, wol);

    dim3 gg(TLEN / 128, DM / 128), blk(256);
    gemm_bx3<<<gg, blk, 0, stream>>>(xh, xl, wqh, wql, bq, nullptr, qh,  ql,  0, TLEN, DM);
    gemm_bx3<<<gg, blk, 0, stream>>>(xh, xl, wkh, wkl, bk, nullptr, kh,  kl,  0, TLEN, DM);
    gemm_bx3<<<gg, blk, 0, stream>>>(xh, xl, wvh, wvl, bv, nullptr, vth, vtl, 1, TLEN, DM);

    attn_mfma<<<dim3(TLEN / 64, NHEAD), blk, 0, stream>>>(qh, ql, kh, kl, vth, vtl, oh, ol, scaling);

    gemm_bx3<<<gg, blk, 0, stream>>>(oh, ol, woh, wol, nullptr, out, nullptr, nullptr, 0, TLEN, DM);
}

// Round 4
// 548.562 us; speedup vs baseline: 4.6365x; 1.1288x over previous
//
#include <hip/hip_runtime.h>
#include <hip/hip_bf16.h>
#include <cstring>

typedef unsigned short u16;
typedef unsigned int   u32;
typedef __attribute__((ext_vector_type(8)))  short bfrag;    // 8 bf16 = 4 VGPR
typedef __attribute__((ext_vector_type(4)))  float ffrag4;   // 16x16 acc
typedef __attribute__((ext_vector_type(16))) float ffrag16;  // 32x32 acc

#define TLEN 4096
#define DM   1024
#define NHEAD 16
#define HD    64

// round-to-nearest-even fp32 -> bf16 (bits)
__device__ __forceinline__ u16 f2bf(float f) {
    u32 u = __float_as_uint(f);
    u32 r = (u + 0x7FFFu + ((u >> 16) & 1u)) >> 16;
    return (u16)r;
}
__device__ __forceinline__ float bf2f(u16 h) { return __uint_as_float(((u32)h) << 16); }

// Schraudolph fast-exp, bit-exact vs reference
__device__ __forceinline__ float fexp_gist(float x) {
    float y = fmaf(12102203.17133801f, x, 1064986823.010288f);
    y = (y < 8388608.0f || y > 2139095040.0f) ? 0.0f : y;
    return __int_as_float((int)y);
}

#define GLD16(gsrc, ldst) \
  __builtin_amdgcn_global_load_lds((const __attribute__((address_space(1))) u32*)(gsrc), \
                                   (__attribute__((address_space(3))) u32*)(ldst), 16, 0, 0)

// ---------------- split fp32 -> (hi, lo) bf16 ----------------
__global__ __launch_bounds__(256) void split_k(const float* __restrict__ a,
                                               u16* __restrict__ hi, u16* __restrict__ lo) {
    int i = (blockIdx.x * 256 + threadIdx.x) * 4;
    float4 v = *(const float4*)&a[i];
    u16 h0 = f2bf(v.x), h1 = f2bf(v.y), h2 = f2bf(v.z), h3 = f2bf(v.w);
    ushort4 hv; hv.x = h0; hv.y = h1; hv.z = h2; hv.w = h3;
    ushort4 lv;
    lv.x = f2bf(v.x - bf2f(h0)); lv.y = f2bf(v.y - bf2f(h1));
    lv.z = f2bf(v.z - bf2f(h2)); lv.w = f2bf(v.w - bf2f(h3));
    *(ushort4*)&hi[i] = hv;
    *(ushort4*)&lo[i] = lv;
}

// ---------------- bf16x3 GEMM with double-buffered prefetch ----------------
// C[M][N] = A[M][1024] * W[N][1024]^T (+bias). 128x128 tile, BK=32, 4 waves.
__global__ __launch_bounds__(256) void gemm_bx3(
    const u16* __restrict__ Ah, const u16* __restrict__ Al,
    const u16* __restrict__ Wh, const u16* __restrict__ Wl,
    const float* __restrict__ bias,
    float* __restrict__ Cf, u16* __restrict__ Chi, u16* __restrict__ Clo,
    int trans, int M, int N)
{
    __shared__ u16 Ash[2][2][4096];   // [buf][hi/lo][128 x 32]
    __shared__ u16 Wsh[2][2][4096];
    const int tid = threadIdx.x;
    const int w = tid >> 6, lane = tid & 63, lr = lane & 15, lg = lane >> 4;
    const int wm = w >> 1, wn = w & 1;
    const int m0 = blockIdx.x * 128, n0 = blockIdx.y * 128;

    ffrag4 acc[4][4];
    #pragma unroll
    for (int i = 0; i < 4; ++i)
        #pragma unroll
        for (int j = 0; j < 4; ++j) acc[i][j] = (ffrag4)(0.0f);

    // prologue stage k0=0 into buf 0
    #pragma unroll
    for (int i = 0; i < 2; ++i) {
        int o   = (i * 256 + tid) * 16;
        int row = o >> 6;
        int sl  = ((o >> 4) & 3) ^ ((row >> 1) & 3);
        const size_t ga = (size_t)(m0 + row) * DM + sl * 8;
        const size_t gw = (size_t)(n0 + row) * DM + sl * 8;
        GLD16(Ah + ga, ((char*)&Ash[0][0][0]) + o);
        GLD16(Al + ga, ((char*)&Ash[0][1][0]) + o);
        GLD16(Wh + gw, ((char*)&Wsh[0][0][0]) + o);
        GLD16(Wl + gw, ((char*)&Wsh[0][1][0]) + o);
    }
    asm volatile("s_waitcnt vmcnt(0)" ::: "memory");
    __syncthreads();

    int buf = 0;
    #pragma unroll 1
    for (int k0 = 0; k0 < DM; k0 += 32) {
        if (k0 + 32 < DM) {           // prefetch next K-step into buf^1
            #pragma unroll
            for (int i = 0; i < 2; ++i) {
                int o   = (i * 256 + tid) * 16;
                int row = o >> 6;
                int sl  = ((o >> 4) & 3) ^ ((row >> 1) & 3);
                const size_t ga = (size_t)(m0 + row) * DM + k0 + 32 + sl * 8;
                const size_t gw = (size_t)(n0 + row) * DM + k0 + 32 + sl * 8;
                GLD16(Ah + ga, ((char*)&Ash[buf ^ 1][0][0]) + o);
                GLD16(Al + ga, ((char*)&Ash[buf ^ 1][1][0]) + o);
                GLD16(Wh + gw, ((char*)&Wsh[buf ^ 1][0][0]) + o);
                GLD16(Wl + gw, ((char*)&Wsh[buf ^ 1][1][0]) + o);
            }
        }
        bfrag ah[4], al[4], bh[4], bl[4];
        #pragma unroll
        for (int f = 0; f < 4; ++f) {
            int ra = wm * 64 + f * 16 + lr;
            int oa = ra * 64 + ((lg ^ ((ra >> 1) & 3)) * 16);
            ah[f] = *(const bfrag*)(((const char*)&Ash[buf][0][0]) + oa);
            al[f] = *(const bfrag*)(((const char*)&Ash[buf][1][0]) + oa);
            int rb = wn * 64 + f * 16 + lr;
            int ob = rb * 64 + ((lg ^ ((rb >> 1) & 3)) * 16);
            bh[f] = *(const bfrag*)(((const char*)&Wsh[buf][0][0]) + ob);
            bl[f] = *(const bfrag*)(((const char*)&Wsh[buf][1][0]) + ob);
        }
        #pragma unroll
        for (int mf = 0; mf < 4; ++mf)
            #pragma unroll
            for (int nf = 0; nf < 4; ++nf) {
                acc[mf][nf] = __builtin_amdgcn_mfma_f32_16x16x32_bf16(ah[mf], bh[nf], acc[mf][nf], 0, 0, 0);
                acc[mf][nf] = __builtin_amdgcn_mfma_f32_16x16x32_bf16(ah[mf], bl[nf], acc[mf][nf], 0, 0, 0);
                acc[mf][nf] = __builtin_amdgcn_mfma_f32_16x16x32_bf16(al[mf], bh[nf], acc[mf][nf], 0, 0, 0);
            }
        asm volatile("s_waitcnt vmcnt(0)" ::: "memory");
        __syncthreads();
        buf ^= 1;
    }

    float bv[4] = {0.f, 0.f, 0.f, 0.f};
    if (bias) {
        #pragma unroll
        for (int nf = 0; nf < 4; ++nf) bv[nf] = bias[n0 + wn * 64 + nf * 16 + lr];
    }
    #pragma unroll
    for (int mf = 0; mf < 4; ++mf)
        #pragma unroll
        for (int nf = 0; nf < 4; ++nf)
            #pragma unroll
            for (int r = 0; r < 4; ++r) {
                int row = m0 + wm * 64 + mf * 16 + lg * 4 + r;
                int col = n0 + wn * 64 + nf * 16 + lr;
                float v = acc[mf][nf][r] + bv[nf];
                if (Cf) Cf[(size_t)row * N + col] = v;
                if (Chi) {
                    u16 h = f2bf(v), l = f2bf(v - bf2f(h));
                    size_t idx = trans ? ((size_t)col * M + row) : ((size_t)row * N + col);
                    Chi[idx] = h; Clo[idx] = l;
                }
            }
}

// ---------------- fused attention: swapped-operand 32x32 MFMA ----------------
// Block = 4 waves; wave w owns 32 q-rows; each lane owns q = lane&31 (h = lane>>5).
// QK^T swapped (S^T = K*Q) -> lane-local softmax; P reaches PV (O^T = V^T * P^T)
// via cvt_pk + v_permlane32_swap (no LDS round-trip). K/V tiles double-buffered.
__global__ __launch_bounds__(256, 2) void attn_mfma(
    const u16* __restrict__ qh_, const u16* __restrict__ ql_,
    const u16* __restrict__ kh_, const u16* __restrict__ kl_,
    const u16* __restrict__ vth_, const u16* __restrict__ vtl_,   // [DM][TLEN]
    u16* __restrict__ oh_, u16* __restrict__ ol_, float scaling)
{
    __shared__ u16 KH[2][4096], KL[2][4096];   // [buf][64 keys x 64 d], slot^=(row&7)
    __shared__ u16 VH[2][4096], VL[2][4096];   // [buf][64 d x 64 keys]

    const int tid = threadIdx.x;
    const int w = tid >> 6, lane = tid & 63;
    const int q32 = lane & 31, h = lane >> 5;
    const int t0 = blockIdx.x * 128, hc = blockIdx.y * HD;
    const int qrow = t0 + w * 32 + q32;

    // Q fragments (B-side: col=q32, k = kd*16 + h*8 + e), loaded once from global
    bfrag qhf[4], qlf[4];
    {
        const size_t qo = (size_t)qrow * DM + hc + h * 8;
        #pragma unroll
        for (int kd = 0; kd < 4; ++kd) {
            qhf[kd] = *(const bfrag*)&qh_[qo + kd * 16];
            qlf[kd] = *(const bfrag*)&ql_[qo + kd * 16];
        }
    }

    // ---- pass 1: global per-q-row max over hi-only scores ----
    {
        #pragma unroll
        for (int i = 0; i < 2; ++i) {
            int o = (i * 256 + tid) * 16, row = o >> 7;
            int sl = ((o >> 4) & 7) ^ (row & 7);
            GLD16(kh_ + (size_t)row * DM + hc + sl * 8, ((char*)&KH[0][0]) + o);
        }
        asm volatile("s_waitcnt vmcnt(0)" ::: "memory");
        __syncthreads();
    }
    float rmax = -3.402823466e38f;
    int buf = 0;
    #pragma unroll 1
    for (int j0 = 0; j0 < TLEN; j0 += 64) {
        if (j0 + 64 < TLEN) {
            #pragma unroll
            for (int i = 0; i < 2; ++i) {
                int o = (i * 256 + tid) * 16, row = o >> 7;
                int sl = ((o >> 4) & 7) ^ (row & 7);
                GLD16(kh_ + (size_t)(j0 + 64 + row) * DM + hc + sl * 8, ((char*)&KH[buf ^ 1][0]) + o);
            }
        }
        #pragma unroll
        for (int F = 0; F < 2; ++F) {
            ffrag16 sf = (ffrag16)(0.0f);
            #pragma unroll
            for (int kd = 0; kd < 4; ++kd) {
                int kr = F * 32 + q32;
                bfrag kf = *(const bfrag*)(((const char*)&KH[buf][0]) + kr * 128 + (((kd * 2 + h) ^ (kr & 7)) * 16));
                sf = __builtin_amdgcn_mfma_f32_32x32x16_bf16(kf, qhf[kd], sf, 0, 0, 0);
            }
            #pragma unroll
            for (int r = 0; r < 16; ++r) rmax = fmaxf(rmax, sf[r]);
        }
        asm volatile("s_waitcnt vmcnt(0)" ::: "memory");
        __syncthreads();
        buf ^= 1;
    }
    rmax = fmaxf(rmax, __shfl_xor(rmax, 32, 64));
    const float nmr = -(rmax * scaling);   // e = gist(s*scale - m)

    // ---- pass 2: bx3 scores -> gist -> permlane exchange -> bx3 PV ----
    ffrag16 oac[2];
    oac[0] = (ffrag16)(0.0f); oac[1] = (ffrag16)(0.0f);
    float se = 0.0f;

    {   // stage tile 0 (all four buffers) into buf 0
        #pragma unroll
        for (int i = 0; i < 2; ++i) {
            int o = (i * 256 + tid) * 16, row = o >> 7;
            int sl = ((o >> 4) & 7) ^ (row & 7);
            const size_t ko = (size_t)row * DM + hc + sl * 8;
            const size_t vo = (size_t)(hc + row) * TLEN + sl * 8;
            GLD16(kh_ + ko, ((char*)&KH[0][0]) + o);
            GLD16(kl_ + ko, ((char*)&KL[0][0]) + o);
            GLD16(vth_ + vo, ((char*)&VH[0][0]) + o);
            GLD16(vtl_ + vo, ((char*)&VL[0][0]) + o);
        }
        asm volatile("s_waitcnt vmcnt(0)" ::: "memory");
        __syncthreads();
    }
    buf = 0;
    #pragma unroll 1
    for (int j0 = 0; j0 < TLEN; j0 += 64) {
        if (j0 + 64 < TLEN) {
            #pragma unroll
            for (int i = 0; i < 2; ++i) {
                int o = (i * 256 + tid) * 16, row = o >> 7;
                int sl = ((o >> 4) & 7) ^ (row & 7);
                const size_t ko = (size_t)(j0 + 64 + row) * DM + hc + sl * 8;
                const size_t vo = (size_t)(hc + row) * TLEN + j0 + 64 + sl * 8;
                GLD16(kh_ + ko, ((char*)&KH[buf ^ 1][0]) + o);
                GLD16(kl_ + ko, ((char*)&KL[buf ^ 1][0]) + o);
                GLD16(vth_ + vo, ((char*)&VH[buf ^ 1][0]) + o);
                GLD16(vtl_ + vo, ((char*)&VL[buf ^ 1][0]) + o);
            }
        }
        // QK^T (swapped): sf[F] holds S^T for keys F*32+row, q = q32
        ffrag16 sf[2];
        #pragma unroll
        for (int F = 0; F < 2; ++F) {
            sf[F] = (ffrag16)(0.0f);
            #pragma unroll
            for (int kd = 0; kd < 4; ++kd) {
                int kr = F * 32 + q32;
                int ob = kr * 128 + (((kd * 2 + h) ^ (kr & 7)) * 16);
                bfrag kf = *(const bfrag*)(((const char*)&KH[buf][0]) + ob);
                bfrag lf = *(const bfrag*)(((const char*)&KL[buf][0]) + ob);
                sf[F] = __builtin_amdgcn_mfma_f32_32x32x16_bf16(kf, qhf[kd], sf[F], 0, 0, 0);
                sf[F] = __builtin_amdgcn_mfma_f32_32x32x16_bf16(lf, qhf[kd], sf[F], 0, 0, 0);
                sf[F] = __builtin_amdgcn_mfma_f32_32x32x16_bf16(kf, qlf[kd], sf[F], 0, 0, 0);
            }
        }
        // gist-exp + pack. Group g=4F+Rq holds keys 8g+4h+{0..3}; packs P*[g][d2].
        u32 PH[8][2], PL[8][2];
        #pragma unroll
        for (int F = 0; F < 2; ++F)
            #pragma unroll
            for (int Rq = 0; Rq < 4; ++Rq)
                #pragma unroll
                for (int d2 = 0; d2 < 2; ++d2) {
                    float e0 = fexp_gist(fmaf(sf[F][Rq * 4 + d2 * 2 + 0], scaling, nmr));
                    float e1 = fexp_gist(fmaf(sf[F][Rq * 4 + d2 * 2 + 1], scaling, nmr));
                    se += e0 + e1;
                    __hip_bfloat162 hb = __float22bfloat162_rn(make_float2(e0, e1));
                    u32 hw; memcpy(&hw, &hb, 4);
                    float r0 = e0 - __uint_as_float(hw << 16);
                    float r1 = e1 - __uint_as_float(hw & 0xffff0000u);
                    __hip_bfloat162 lb = __float22bfloat162_rn(make_float2(r0, r1));
                    u32 lw; memcpy(&lw, &lb, 4);
                    PH[F * 4 + Rq][d2] = hw;
                    PL[F * 4 + Rq][d2] = lw;
                }
        // exchange + PV: per k-16 step kt, frag word delta = swap(P[2kt][d], P[2kt+1][d])
        #pragma unroll
        for (int kt = 0; kt < 4; ++kt) {
            u32 a0 = PH[2 * kt][0], b0 = PH[2 * kt + 1][0];
            u32 a1 = PH[2 * kt][1], b1 = PH[2 * kt + 1][1];
            asm volatile("v_permlane32_swap_b32 %0, %1" : "+v"(a0), "+v"(b0));
            asm volatile("v_permlane32_swap_b32 %0, %1" : "+v"(a1), "+v"(b1));
            u32 c0 = PL[2 * kt][0], d0 = PL[2 * kt + 1][0];
            u32 c1 = PL[2 * kt][1], d1 = PL[2 * kt + 1][1];
            asm volatile("v_permlane32_swap_b32 %0, %1" : "+v"(c0), "+v"(d0));
            asm volatile("v_permlane32_swap_b32 %0, %1" : "+v"(c1), "+v"(d1));
            union { u32 u[4]; bfrag f; } ph, pl;
            ph.u[0] = a0; ph.u[1] = a1; ph.u[2] = b0; ph.u[3] = b1;
            pl.u[0] = c0; pl.u[1] = c1; pl.u[2] = d0; pl.u[3] = d1;
            #pragma unroll
            for (int Fd = 0; Fd < 2; ++Fd) {
                int vr = Fd * 32 + q32;
                int ov = vr * 128 + (((kt * 2 + h) ^ (vr & 7)) * 16);
                bfrag vh = *(const bfrag*)(((const char*)&VH[buf][0]) + ov);
                bfrag vl = *(const bfrag*)(((const char*)&VL[buf][0]) + ov);
                oac[Fd] = __builtin_amdgcn_mfma_f32_32x32x16_bf16(vh, ph.f, oac[Fd], 0, 0, 0);
                oac[Fd] = __builtin_amdgcn_mfma_f32_32x32x16_bf16(vl, ph.f, oac[Fd], 0, 0, 0);
                oac[Fd] = __builtin_amdgcn_mfma_f32_32x32x16_bf16(vh, pl.f, oac[Fd], 0, 0, 0);
            }
        }
        asm volatile("s_waitcnt vmcnt(0)" ::: "memory");
        __syncthreads();
        buf ^= 1;
    }

    se += __shfl_xor(se, 32, 64);
    const float inv = 1.0f / se;
    // O^T frag: col=q32, row d = (r&3)+8*(r>>2)+4h (+32*Fd): 4 consecutive d per Rq
    #pragma unroll
    for (int Fd = 0; Fd < 2; ++Fd)
        #pragma unroll
        for (int Rq = 0; Rq < 4; ++Rq) {
            ushort4 hv, lv;
            #pragma unroll
            for (int m = 0; m < 4; ++m) {
                float v = oac[Fd][Rq * 4 + m] * inv;
                u16 hh = f2bf(v);
                ((u16*)&hv)[m] = hh;
                ((u16*)&lv)[m] = f2bf(v - bf2f(hh));
            }
            size_t off = (size_t)qrow * DM + hc + Fd * 32 + Rq * 8 + h * 4;
            *(ushort4*)&oh_[off] = hv;
            *(ushort4*)&ol_[off] = lv;
        }
}

extern "C" void kernel_launch(void* const* d_in, const int* in_sizes, int n_in,
                              void* d_out, int out_size, void* d_ws, size_t ws_size,
                              hipStream_t stream)
{
    const float* x  = (const float*)d_in[0];
    const float* Wq = (const float*)d_in[1];
    const float* bq = (const float*)d_in[2];
    const float* Wk = (const float*)d_in[3];
    const float* bk = (const float*)d_in[4];
    const float* Wv = (const float*)d_in[5];
    const float* bv = (const float*)d_in[6];
    const float* Wo = (const float*)d_in[7];
    float* out = (float*)d_out;

    // workspace layout (bf16 halves), 80 MB total
    u16* p = (u16*)d_ws;
    u16* xh  = p; p += (size_t)TLEN * DM;
    u16* xl  = p; p += (size_t)TLEN * DM;
    u16* wqh = p; p += (size_t)DM * DM;  u16* wql = p; p += (size_t)DM * DM;
    u16* wkh = p; p += (size_t)DM * DM;  u16* wkl = p; p += (size_t)DM * DM;
    u16* wvh = p; p += (size_t)DM * DM;  u16* wvl = p; p += (size_t)DM * DM;
    u16* woh = p; p += (size_t)DM * DM;  u16* wol = p; p += (size_t)DM * DM;
    u16* qh  = p; p += (size_t)TLEN * DM;  u16* ql  = p; p += (size_t)TLEN * DM;
    u16* kh  = p; p += (size_t)TLEN * DM;  u16* kl  = p; p += (size_t)TLEN * DM;
    u16* vth = p; p += (size_t)TLEN * DM;  u16* vtl = p; p += (size_t)TLEN * DM;
    u16* oh = xh;  u16* ol = xl;   // x fully consumed before attn writes o

    // Quake fast-rsqrt(HEAD_DIM), bit-exact vs reference (host-side)
    float hx = (float)HD;
    int bi; memcpy(&bi, &hx, 4);
    bi = (int)(0x5F3759DFLL - ((long long)bi >> 1));
    float yy; memcpy(&yy, &bi, 4);
    float scaling = yy * (1.5f - 0.5f * hx * yy * yy);

    split_k<<<4096, 256, 0, stream>>>(x,  xh,  xl);
    split_k<<<1024, 256, 0, stream>>>(Wq, wqh, wql);
    split_k<<<1024, 256, 0, stream>>>(Wk, wkh, wkl);
    split_k<<<1024, 256, 0, stream>>>(Wv, wvh, wvl);
    split_k<<<1024, 256, 0, stream>>>(Wo, woh, wol);

    dim3 gg(TLEN / 128, DM / 128), blk(256);
    gemm_bx3<<<gg, blk, 0, stream>>>(xh, xl, wqh, wql, bq, nullptr, qh,  ql,  0, TLEN, DM);
    gemm_bx3<<<gg, blk, 0, stream>>>(xh, xl, wkh, wkl, bk, nullptr, kh,  kl,  0, TLEN, DM);
    gemm_bx3<<<gg, blk, 0, stream>>>(xh, xl, wvh, wvl, bv, nullptr, vth, vtl, 1, TLEN, DM);

    attn_mfma<<<dim3(TLEN / 128, NHEAD), blk, 0, stream>>>(qh, ql, kh, kl, vth, vtl, oh, ol, scaling);

    gemm_bx3<<<gg, blk, 0, stream>>>(oh, ol, woh, wol, nullptr, out, nullptr, nullptr, 0, TLEN, DM);
}

// Round 5
// 481.907 us; speedup vs baseline: 5.2778x; 1.1383x over previous
//
#include <hip/hip_runtime.h>
#include <hip/hip_bf16.h>
#include <cstring>

typedef unsigned short u16;
typedef unsigned int   u32;
typedef __attribute__((ext_vector_type(8)))  short bfrag;    // 8 bf16 = 4 VGPR
typedef __attribute__((ext_vector_type(4)))  float ffrag4;   // 16x16 acc
typedef __attribute__((ext_vector_type(16))) float ffrag16;  // 32x32 acc

#define TLEN 4096
#define DM   1024
#define NHEAD 16
#define HD    64

__device__ __forceinline__ u16 f2bf(float f) {
    u32 u = __float_as_uint(f);
    u32 r = (u + 0x7FFFu + ((u >> 16) & 1u)) >> 16;
    return (u16)r;
}
__device__ __forceinline__ float bf2f(u16 h) { return __uint_as_float(((u32)h) << 16); }

// Schraudolph fast-exp, bit-exact vs reference
__device__ __forceinline__ float fexp_gist(float x) {
    float y = fmaf(12102203.17133801f, x, 1064986823.010288f);
    y = (y < 8388608.0f || y > 2139095040.0f) ? 0.0f : y;
    return __int_as_float((int)y);
}

#define GLD16(gsrc, ldst) \
  __builtin_amdgcn_global_load_lds((const __attribute__((address_space(1))) u32*)(gsrc), \
                                   (__attribute__((address_space(3))) u32*)(ldst), 16, 0, 0)

// ---------------- split fp32 -> (hi, lo) bf16 ----------------
__global__ __launch_bounds__(256) void split_x(const float* __restrict__ a,
                                               u16* __restrict__ hi, u16* __restrict__ lo) {
    int i = (blockIdx.x * 256 + threadIdx.x) * 4;
    float4 v = *(const float4*)&a[i];
    u16 h0 = f2bf(v.x), h1 = f2bf(v.y), h2 = f2bf(v.z), h3 = f2bf(v.w);
    ushort4 hv; hv.x = h0; hv.y = h1; hv.z = h2; hv.w = h3;
    ushort4 lv;
    lv.x = f2bf(v.x - bf2f(h0)); lv.y = f2bf(v.y - bf2f(h1));
    lv.z = f2bf(v.z - bf2f(h2)); lv.w = f2bf(v.w - bf2f(h3));
    *(ushort4*)&hi[i] = hv;
    *(ushort4*)&lo[i] = lv;
}

struct SplitPtrs { const float* src[4]; u16* hi[4]; u16* lo[4]; };
__global__ __launch_bounds__(256) void split_w(SplitPtrs P) {
    int m = blockIdx.y;
    int i = (blockIdx.x * 256 + threadIdx.x) * 4;
    float4 v = *(const float4*)&P.src[m][i];
    u16 h0 = f2bf(v.x), h1 = f2bf(v.y), h2 = f2bf(v.z), h3 = f2bf(v.w);
    ushort4 hv; hv.x = h0; hv.y = h1; hv.z = h2; hv.w = h3;
    ushort4 lv;
    lv.x = f2bf(v.x - bf2f(h0)); lv.y = f2bf(v.y - bf2f(h1));
    lv.z = f2bf(v.z - bf2f(h2)); lv.w = f2bf(v.w - bf2f(h3));
    *(ushort4*)&P.hi[m][i] = hv;
    *(ushort4*)&P.lo[m][i] = lv;
}

// ---------------- bf16x3 GEMM body (128x128 tile, BK=32, 4 waves) ----------------
// C = A[M][1024] * W[N][1024]^T (+bias); dbuf prefetch via global_load_lds.
__device__ __forceinline__ void gemm_body(
    const u16* __restrict__ Ah, const u16* __restrict__ Al,
    const u16* __restrict__ Wh, const u16* __restrict__ Wl,
    const float* __restrict__ bias,
    float* __restrict__ Cf, u16* __restrict__ Chi, u16* __restrict__ Clo,
    int trans, int M, int N, int m0, int n0,
    u16 (*Ash)[2][4096], u16 (*Wsh)[2][4096])
{
    const int tid = threadIdx.x;
    const int w = tid >> 6, lane = tid & 63, lr = lane & 15, lg = lane >> 4;
    const int wm = w >> 1, wn = w & 1;

    ffrag4 acc[4][4];
    #pragma unroll
    for (int i = 0; i < 4; ++i)
        #pragma unroll
        for (int j = 0; j < 4; ++j) acc[i][j] = (ffrag4)(0.0f);

    #pragma unroll
    for (int i = 0; i < 2; ++i) {
        int o   = (i * 256 + tid) * 16;
        int row = o >> 6;
        int sl  = ((o >> 4) & 3) ^ ((row >> 1) & 3);
        const size_t ga = (size_t)(m0 + row) * DM + sl * 8;
        const size_t gw = (size_t)(n0 + row) * DM + sl * 8;
        GLD16(Ah + ga, ((char*)&Ash[0][0][0]) + o);
        GLD16(Al + ga, ((char*)&Ash[0][1][0]) + o);
        GLD16(Wh + gw, ((char*)&Wsh[0][0][0]) + o);
        GLD16(Wl + gw, ((char*)&Wsh[0][1][0]) + o);
    }
    asm volatile("s_waitcnt vmcnt(0)" ::: "memory");
    __syncthreads();

    int buf = 0;
    #pragma unroll 1
    for (int k0 = 0; k0 < DM; k0 += 32) {
        if (k0 + 32 < DM) {
            #pragma unroll
            for (int i = 0; i < 2; ++i) {
                int o   = (i * 256 + tid) * 16;
                int row = o >> 6;
                int sl  = ((o >> 4) & 3) ^ ((row >> 1) & 3);
                const size_t ga = (size_t)(m0 + row) * DM + k0 + 32 + sl * 8;
                const size_t gw = (size_t)(n0 + row) * DM + k0 + 32 + sl * 8;
                GLD16(Ah + ga, ((char*)&Ash[buf ^ 1][0][0]) + o);
                GLD16(Al + ga, ((char*)&Ash[buf ^ 1][1][0]) + o);
                GLD16(Wh + gw, ((char*)&Wsh[buf ^ 1][0][0]) + o);
                GLD16(Wl + gw, ((char*)&Wsh[buf ^ 1][1][0]) + o);
            }
        }
        bfrag ah[4], al[4], bh[4], bl[4];
        #pragma unroll
        for (int f = 0; f < 4; ++f) {
            int ra = wm * 64 + f * 16 + lr;
            int oa = ra * 64 + ((lg ^ ((ra >> 1) & 3)) * 16);
            ah[f] = *(const bfrag*)(((const char*)&Ash[buf][0][0]) + oa);
            al[f] = *(const bfrag*)(((const char*)&Ash[buf][1][0]) + oa);
            int rb = wn * 64 + f * 16 + lr;
            int ob = rb * 64 + ((lg ^ ((rb >> 1) & 3)) * 16);
            bh[f] = *(const bfrag*)(((const char*)&Wsh[buf][0][0]) + ob);
            bl[f] = *(const bfrag*)(((const char*)&Wsh[buf][1][0]) + ob);
        }
        #pragma unroll
        for (int mf = 0; mf < 4; ++mf)
            #pragma unroll
            for (int nf = 0; nf < 4; ++nf) {
                acc[mf][nf] = __builtin_amdgcn_mfma_f32_16x16x32_bf16(ah[mf], bh[nf], acc[mf][nf], 0, 0, 0);
                acc[mf][nf] = __builtin_amdgcn_mfma_f32_16x16x32_bf16(ah[mf], bl[nf], acc[mf][nf], 0, 0, 0);
                acc[mf][nf] = __builtin_amdgcn_mfma_f32_16x16x32_bf16(al[mf], bh[nf], acc[mf][nf], 0, 0, 0);
            }
        asm volatile("s_waitcnt vmcnt(0)" ::: "memory");
        __syncthreads();
        buf ^= 1;
    }

    float bv[4] = {0.f, 0.f, 0.f, 0.f};
    if (bias) {
        #pragma unroll
        for (int nf = 0; nf < 4; ++nf) bv[nf] = bias[n0 + wn * 64 + nf * 16 + lr];
    }
    #pragma unroll
    for (int mf = 0; mf < 4; ++mf)
        #pragma unroll
        for (int nf = 0; nf < 4; ++nf)
            #pragma unroll
            for (int r = 0; r < 4; ++r) {
                int row = m0 + wm * 64 + mf * 16 + lg * 4 + r;
                int col = n0 + wn * 64 + nf * 16 + lr;
                float v = acc[mf][nf][r] + bv[nf];
                if (Cf) Cf[(size_t)row * N + col] = v;
                if (Chi) {
                    u16 hh = f2bf(v), ll = f2bf(v - bf2f(hh));
                    size_t idx = trans ? ((size_t)col * M + row) : ((size_t)row * N + col);
                    Chi[idx] = hh; Clo[idx] = ll;
                }
            }
}

// out-projection (fp32 out)
__global__ __launch_bounds__(256) void gemm_bx3(
    const u16* __restrict__ Ah, const u16* __restrict__ Al,
    const u16* __restrict__ Wh, const u16* __restrict__ Wl,
    float* __restrict__ Cf)
{
    __shared__ u16 Ash[2][2][4096];
    __shared__ u16 Wsh[2][2][4096];
    gemm_body(Ah, Al, Wh, Wl, nullptr, Cf, nullptr, nullptr, 0, TLEN, DM,
              blockIdx.x * 128, blockIdx.y * 128, Ash, Wsh);
}

// fused Q/K/V projections: grid (32, 24); mat = by>>3
struct QkvPtrs {
    const u16* Wh[3]; const u16* Wl[3]; const float* b[3];
    u16* Ch[3]; u16* Cl[3];
};
__global__ __launch_bounds__(256, 3) void gemm_qkv(
    const u16* __restrict__ Ah, const u16* __restrict__ Al, QkvPtrs P)
{
    __shared__ u16 Ash[2][2][4096];
    __shared__ u16 Wsh[2][2][4096];
    const int mat = blockIdx.y >> 3;
    const int n0 = (blockIdx.y & 7) * 128;
    gemm_body(Ah, Al, P.Wh[mat], P.Wl[mat], P.b[mat],
              nullptr, P.Ch[mat], P.Cl[mat], (mat == 2) ? 1 : 0, TLEN, DM,
              blockIdx.x * 128, n0, Ash, Wsh);
}

// ---------------- fused attention: 8-wave K-split, swapped 32x32 MFMA ----------------
// Block = 512 thr = 8 waves. Wave (wq = w&3, wg = w>>2): q-rows t0+wq*32+[0,32),
// key-half wg of each 64-key window. Lane-local softmax (q = lane&31);
// P -> PV via cvt_pk + v_permlane32_swap. Partial (max / O / sum-e) combined in LDS.
__global__ __launch_bounds__(512, 4) void attn_mfma(
    const u16* __restrict__ qh_, const u16* __restrict__ ql_,
    const u16* __restrict__ kh_, const u16* __restrict__ kl_,
    const u16* __restrict__ vth_, const u16* __restrict__ vtl_,   // [DM][TLEN]
    u16* __restrict__ oh_, u16* __restrict__ ol_, float scaling)
{
    // [0..1]=KH bufs, [2..3]=KL, [4..5]=VH, [6..7]=VL (8KB each, 64KB total)
    __shared__ u16 SMEM[8][4096];

    const int tid = threadIdx.x;
    const int w = tid >> 6, lane = tid & 63;
    const int q32 = lane & 31, h = lane >> 5;
    const int wq = w & 3, wg = w >> 2;
    const int t0 = blockIdx.x * 128, hc = blockIdx.y * HD;
    const int qrow = t0 + wq * 32 + q32;

    const int srow = tid >> 3;                 // staging row 0..63 (512 thr x 16B = 8KB)
    const int ssl  = (tid & 7) ^ (srow & 7);   // swizzled 16B slot
    const int so   = tid * 16;                 // LDS byte offset

    // Q fragments (B-side: col=q32, k = kd*16 + h*8 + e)
    bfrag qhf[4], qlf[4];
    {
        const size_t qo = (size_t)qrow * DM + hc + h * 8;
        #pragma unroll
        for (int kd = 0; kd < 4; ++kd) {
            qhf[kd] = *(const bfrag*)&qh_[qo + kd * 16];
            qlf[kd] = *(const bfrag*)&ql_[qo + kd * 16];
        }
    }

    // ---- pass 1: per-q-row max of hi-only scores over this wave's key half ----
    GLD16(kh_ + (size_t)srow * DM + hc + ssl * 8, ((char*)&SMEM[0][0]) + so);
    asm volatile("s_waitcnt vmcnt(0)" ::: "memory");
    __syncthreads();

    float rmax = -3.402823466e38f;
    int buf = 0;
    #pragma unroll 1
    for (int j0 = 0; j0 < TLEN; j0 += 64) {
        if (j0 + 64 < TLEN)
            GLD16(kh_ + (size_t)(j0 + 64 + srow) * DM + hc + ssl * 8,
                  ((char*)&SMEM[buf ^ 1][0]) + so);
        ffrag16 sf = (ffrag16)(0.0f);
        const int kr = wg * 32 + q32;
        #pragma unroll
        for (int kd = 0; kd < 4; ++kd) {
            bfrag kf = *(const bfrag*)(((const char*)&SMEM[buf][0]) + kr * 128 + (((kd * 2 + h) ^ (kr & 7)) * 16));
            sf = __builtin_amdgcn_mfma_f32_32x32x16_bf16(kf, qhf[kd], sf, 0, 0, 0);
        }
        #pragma unroll
        for (int r = 0; r < 16; ++r) rmax = fmaxf(rmax, sf[r]);
        asm volatile("s_waitcnt vmcnt(0)" ::: "memory");
        __syncthreads();
        buf ^= 1;
    }
    rmax = fmaxf(rmax, __shfl_xor(rmax, 32, 64));

    // combine max across the wave pair (wg=0 / wg=1) via VL-buf1 scratch
    {
        float* MxA = (float*)&SMEM[7][0];        // wg1 partials [4][32]
        float* MxB = MxA + 128;                  // finals       [4][32]
        if (wg == 1 && lane < 32) MxA[wq * 32 + q32] = rmax;
        __syncthreads();
        if (wg == 0) {
            rmax = fmaxf(rmax, MxA[wq * 32 + q32]);
            if (lane < 32) MxB[wq * 32 + q32] = rmax;
        }
        __syncthreads();
        rmax = MxB[wq * 32 + q32];
    }
    const float nmr = -(rmax * scaling);

    // ---- pass 2: bx3 scores -> gist -> permlane exchange -> bx3 PV (partial) ----
    ffrag16 oac[2];
    oac[0] = (ffrag16)(0.0f); oac[1] = (ffrag16)(0.0f);
    float se = 0.0f;

    {
        const size_t ko = (size_t)srow * DM + hc + ssl * 8;
        const size_t vo = (size_t)(hc + srow) * TLEN + ssl * 8;
        GLD16(kh_ + ko, ((char*)&SMEM[0][0]) + so);
        GLD16(kl_ + ko, ((char*)&SMEM[2][0]) + so);
        GLD16(vth_ + vo, ((char*)&SMEM[4][0]) + so);
        GLD16(vtl_ + vo, ((char*)&SMEM[6][0]) + so);
        asm volatile("s_waitcnt vmcnt(0)" ::: "memory");
        __syncthreads();
    }
    buf = 0;
    #pragma unroll 1
    for (int j0 = 0; j0 < TLEN; j0 += 64) {
        if (j0 + 64 < TLEN) {
            const size_t ko = (size_t)(j0 + 64 + srow) * DM + hc + ssl * 8;
            const size_t vo = (size_t)(hc + srow) * TLEN + j0 + 64 + ssl * 8;
            GLD16(kh_ + ko, ((char*)&SMEM[0 + (buf ^ 1)][0]) + so);
            GLD16(kl_ + ko, ((char*)&SMEM[2 + (buf ^ 1)][0]) + so);
            GLD16(vth_ + vo, ((char*)&SMEM[4 + (buf ^ 1)][0]) + so);
            GLD16(vtl_ + vo, ((char*)&SMEM[6 + (buf ^ 1)][0]) + so);
        }
        // QK^T (swapped): sf = S^T for keys wg*32+crow, q = q32
        ffrag16 sf = (ffrag16)(0.0f);
        {
            const int kr = wg * 32 + q32;
            #pragma unroll
            for (int kd = 0; kd < 4; ++kd) {
                int ob = kr * 128 + (((kd * 2 + h) ^ (kr & 7)) * 16);
                bfrag kf = *(const bfrag*)(((const char*)&SMEM[0 + buf][0]) + ob);
                bfrag lf = *(const bfrag*)(((const char*)&SMEM[2 + buf][0]) + ob);
                sf = __builtin_amdgcn_mfma_f32_32x32x16_bf16(kf, qhf[kd], sf, 0, 0, 0);
                sf = __builtin_amdgcn_mfma_f32_32x32x16_bf16(lf, qhf[kd], sf, 0, 0, 0);
                sf = __builtin_amdgcn_mfma_f32_32x32x16_bf16(kf, qlf[kd], sf, 0, 0, 0);
            }
        }
        // gist-exp + pack: group g holds keys wg*32 + 8g + 4h + {0..3}
        u32 PH[4][2], PL[4][2];
        #pragma unroll
        for (int g = 0; g < 4; ++g)
            #pragma unroll
            for (int d2 = 0; d2 < 2; ++d2) {
                float e0 = fexp_gist(fmaf(sf[g * 4 + d2 * 2 + 0], scaling, nmr));
                float e1 = fexp_gist(fmaf(sf[g * 4 + d2 * 2 + 1], scaling, nmr));
                se += e0 + e1;
                __hip_bfloat162 hb = __float22bfloat162_rn(make_float2(e0, e1));
                u32 hw; memcpy(&hw, &hb, 4);
                float r0 = e0 - __uint_as_float(hw << 16);
                float r1 = e1 - __uint_as_float(hw & 0xffff0000u);
                __hip_bfloat162 lb = __float22bfloat162_rn(make_float2(r0, r1));
                u32 lw; memcpy(&lw, &lb, 4);
                PH[g][d2] = hw;
                PL[g][d2] = lw;
            }
        // exchange + PV over this wave's 32 keys (kt = two 16-key steps)
        #pragma unroll
        for (int kt = 0; kt < 2; ++kt) {
            u32 a0 = PH[2 * kt][0], b0 = PH[2 * kt + 1][0];
            u32 a1 = PH[2 * kt][1], b1 = PH[2 * kt + 1][1];
            asm volatile("v_permlane32_swap_b32 %0, %1" : "+v"(a0), "+v"(b0));
            asm volatile("v_permlane32_swap_b32 %0, %1" : "+v"(a1), "+v"(b1));
            u32 c0 = PL[2 * kt][0], d0 = PL[2 * kt + 1][0];
            u32 c1 = PL[2 * kt][1], d1 = PL[2 * kt + 1][1];
            asm volatile("v_permlane32_swap_b32 %0, %1" : "+v"(c0), "+v"(d0));
            asm volatile("v_permlane32_swap_b32 %0, %1" : "+v"(c1), "+v"(d1));
            union { u32 u[4]; bfrag f; } ph, pl;
            ph.u[0] = a0; ph.u[1] = a1; ph.u[2] = b0; ph.u[3] = b1;
            pl.u[0] = c0; pl.u[1] = c1; pl.u[2] = d0; pl.u[3] = d1;
            #pragma unroll
            for (int Fd = 0; Fd < 2; ++Fd) {
                int vr = Fd * 32 + q32;
                int ov = vr * 128 + (((wg * 4 + kt * 2 + h) ^ (vr & 7)) * 16);
                bfrag vh = *(const bfrag*)(((const char*)&SMEM[4 + buf][0]) + ov);
                bfrag vl = *(const bfrag*)(((const char*)&SMEM[6 + buf][0]) + ov);
                oac[Fd] = __builtin_amdgcn_mfma_f32_32x32x16_bf16(vh, ph.f, oac[Fd], 0, 0, 0);
                oac[Fd] = __builtin_amdgcn_mfma_f32_32x32x16_bf16(vl, ph.f, oac[Fd], 0, 0, 0);
                oac[Fd] = __builtin_amdgcn_mfma_f32_32x32x16_bf16(vh, pl.f, oac[Fd], 0, 0, 0);
            }
        }
        asm volatile("s_waitcnt vmcnt(0)" ::: "memory");
        __syncthreads();
        buf ^= 1;
    }

    se += __shfl_xor(se, 32, 64);

    // ---- combine wave-pair partials (exact fp32 adds; same global max) ----
    float* S = (float*)&SMEM[0][0];   // 32KB oac + 1KB se scratch
    if (wg == 1) {
        #pragma unroll
        for (int Fd = 0; Fd < 2; ++Fd)
            #pragma unroll
            for (int r = 0; r < 16; ++r)
                S[((wq * 32 + Fd * 16 + r) * 64) + lane] = oac[Fd][r];
        S[8192 + wq * 64 + lane] = se;
    }
    __syncthreads();
    if (wg == 0) {
        se += S[8192 + wq * 64 + lane];
        const float inv = 1.0f / se;
        #pragma unroll
        for (int Fd = 0; Fd < 2; ++Fd)
            #pragma unroll
            for (int Rq = 0; Rq < 4; ++Rq) {
                ushort4 hv, lv;
                #pragma unroll
                for (int m = 0; m < 4; ++m) {
                    float v = (oac[Fd][Rq * 4 + m] +
                               S[((wq * 32 + Fd * 16 + Rq * 4 + m) * 64) + lane]) * inv;
                    u16 hh = f2bf(v);
                    ((u16*)&hv)[m] = hh;
                    ((u16*)&lv)[m] = f2bf(v - bf2f(hh));
                }
                size_t off = (size_t)qrow * DM + hc + Fd * 32 + Rq * 8 + h * 4;
                *(ushort4*)&oh_[off] = hv;
                *(ushort4*)&ol_[off] = lv;
            }
    }
}

extern "C" void kernel_launch(void* const* d_in, const int* in_sizes, int n_in,
                              void* d_out, int out_size, void* d_ws, size_t ws_size,
                              hipStream_t stream)
{
    const float* x  = (const float*)d_in[0];
    const float* Wq = (const float*)d_in[1];
    const float* bq = (const float*)d_in[2];
    const float* Wk = (const float*)d_in[3];
    const float* bk = (const float*)d_in[4];
    const float* Wv = (const float*)d_in[5];
    const float* bv = (const float*)d_in[6];
    const float* Wo = (const float*)d_in[7];
    float* out = (float*)d_out;

    // workspace layout (bf16 halves), 80 MB total
    u16* p = (u16*)d_ws;
    u16* xh  = p; p += (size_t)TLEN * DM;
    u16* xl  = p; p += (size_t)TLEN * DM;
    u16* wqh = p; p += (size_t)DM * DM;  u16* wql = p; p += (size_t)DM * DM;
    u16* wkh = p; p += (size_t)DM * DM;  u16* wkl = p; p += (size_t)DM * DM;
    u16* wvh = p; p += (size_t)DM * DM;  u16* wvl = p; p += (size_t)DM * DM;
    u16* woh = p; p += (size_t)DM * DM;  u16* wol = p; p += (size_t)DM * DM;
    u16* qh  = p; p += (size_t)TLEN * DM;  u16* ql  = p; p += (size_t)TLEN * DM;
    u16* kh  = p; p += (size_t)TLEN * DM;  u16* kl  = p; p += (size_t)TLEN * DM;
    u16* vth = p; p += (size_t)TLEN * DM;  u16* vtl = p; p += (size_t)TLEN * DM;
    u16* oh = xh;  u16* ol = xl;   // x fully consumed before attn writes o

    // Quake fast-rsqrt(HEAD_DIM), bit-exact vs reference (host-side)
    float hx = (float)HD;
    int bi; memcpy(&bi, &hx, 4);
    bi = (int)(0x5F3759DFLL - ((long long)bi >> 1));
    float yy; memcpy(&yy, &bi, 4);
    float scaling = yy * (1.5f - 0.5f * hx * yy * yy);

    split_x<<<4096, 256, 0, stream>>>(x, xh, xl);
    SplitPtrs SP;
    SP.src[0] = Wq; SP.src[1] = Wk; SP.src[2] = Wv; SP.src[3] = Wo;
    SP.hi[0] = wqh; SP.hi[1] = wkh; SP.hi[2] = wvh; SP.hi[3] = woh;
    SP.lo[0] = wql; SP.lo[1] = wkl; SP.lo[2] = wvl; SP.lo[3] = wol;
    split_w<<<dim3(1024, 4), 256, 0, stream>>>(SP);

    QkvPtrs QP;
    QP.Wh[0] = wqh; QP.Wh[1] = wkh; QP.Wh[2] = wvh;
    QP.Wl[0] = wql; QP.Wl[1] = wkl; QP.Wl[2] = wvl;
    QP.b[0] = bq; QP.b[1] = bk; QP.b[2] = bv;
    QP.Ch[0] = qh; QP.Ch[1] = kh; QP.Ch[2] = vth;
    QP.Cl[0] = ql; QP.Cl[1] = kl; QP.Cl[2] = vtl;
    gemm_qkv<<<dim3(TLEN / 128, 24), 256, 0, stream>>>(xh, xl, QP);

    attn_mfma<<<dim3(TLEN / 128, NHEAD), 512, 0, stream>>>(qh, ql, kh, kl, vth, vtl, oh, ol, scaling);

    gemm_bx3<<<dim3(TLEN / 128, DM / 128), 256, 0, stream>>>(oh, ol, woh, wol, out);
}

// Round 6
// 461.824 us; speedup vs baseline: 5.5073x; 1.0435x over previous
//
#include <hip/hip_runtime.h>
#include <hip/hip_bf16.h>
#include <cstring>

typedef unsigned short u16;
typedef unsigned int   u32;
typedef __attribute__((ext_vector_type(8)))  short bfrag;    // 8 bf16 = 4 VGPR
typedef __attribute__((ext_vector_type(4)))  float ffrag4;   // 16x16 acc
typedef __attribute__((ext_vector_type(16))) float ffrag16;  // 32x32 acc

#define TLEN 4096
#define DM   1024
#define NHEAD 16
#define HD    64

__device__ __forceinline__ u16 f2bf(float f) {
    u32 u = __float_as_uint(f);
    u32 r = (u + 0x7FFFu + ((u >> 16) & 1u)) >> 16;
    return (u16)r;
}
__device__ __forceinline__ float bf2f(u16 h) { return __uint_as_float(((u32)h) << 16); }

#define GLD16(gsrc, ldst) \
  __builtin_amdgcn_global_load_lds((const __attribute__((address_space(1))) u32*)(gsrc), \
                                   (__attribute__((address_space(3))) u32*)(ldst), 16, 0, 0)

// ---------------- split fp32 -> (hi, lo) bf16 ----------------
__global__ __launch_bounds__(256) void split_x(const float* __restrict__ a,
                                               u16* __restrict__ hi, u16* __restrict__ lo) {
    int i = (blockIdx.x * 256 + threadIdx.x) * 4;
    float4 v = *(const float4*)&a[i];
    u16 h0 = f2bf(v.x), h1 = f2bf(v.y), h2 = f2bf(v.z), h3 = f2bf(v.w);
    ushort4 hv; hv.x = h0; hv.y = h1; hv.z = h2; hv.w = h3;
    ushort4 lv;
    lv.x = f2bf(v.x - bf2f(h0)); lv.y = f2bf(v.y - bf2f(h1));
    lv.z = f2bf(v.z - bf2f(h2)); lv.w = f2bf(v.w - bf2f(h3));
    *(ushort4*)&hi[i] = hv;
    *(ushort4*)&lo[i] = lv;
}

struct SplitPtrs { const float* src[4]; u16* hi[4]; u16* lo[4]; };
__global__ __launch_bounds__(256) void split_w(SplitPtrs P) {
    int m = blockIdx.y;
    int i = (blockIdx.x * 256 + threadIdx.x) * 4;
    float4 v = *(const float4*)&P.src[m][i];
    u16 h0 = f2bf(v.x), h1 = f2bf(v.y), h2 = f2bf(v.z), h3 = f2bf(v.w);
    ushort4 hv; hv.x = h0; hv.y = h1; hv.z = h2; hv.w = h3;
    ushort4 lv;
    lv.x = f2bf(v.x - bf2f(h0)); lv.y = f2bf(v.y - bf2f(h1));
    lv.z = f2bf(v.z - bf2f(h2)); lv.w = f2bf(v.w - bf2f(h3));
    *(ushort4*)&P.hi[m][i] = hv;
    *(ushort4*)&P.lo[m][i] = lv;
}

// ---------------- bf16x3 GEMM body (128x128 tile, BK=32, 4 waves, unroll-2) ----------------
#define GSTAGE(BUF, K0) do { \
    _Pragma("unroll") \
    for (int i_ = 0; i_ < 2; ++i_) { \
        int o_ = (i_ * 256 + tid) * 16; \
        int row_ = o_ >> 6; \
        int sl_ = ((o_ >> 4) & 3) ^ ((row_ >> 1) & 3); \
        const size_t ga_ = (size_t)(m0 + row_) * DM + (K0) + sl_ * 8; \
        const size_t gw_ = (size_t)(n0 + row_) * DM + (K0) + sl_ * 8; \
        GLD16(Ah + ga_, ((char*)&Ash[BUF][0][0]) + o_); \
        GLD16(Al + ga_, ((char*)&Ash[BUF][1][0]) + o_); \
        GLD16(Wh + gw_, ((char*)&Wsh[BUF][0][0]) + o_); \
        GLD16(Wl + gw_, ((char*)&Wsh[BUF][1][0]) + o_); \
    } } while (0)

#define GCOMPUTE(BUF) do { \
    bfrag ah[4], al[4], bh[4], bl[4]; \
    _Pragma("unroll") \
    for (int f_ = 0; f_ < 4; ++f_) { \
        ah[f_] = *(const bfrag*)(((const char*)&Ash[BUF][0][0]) + oaf[f_]); \
        al[f_] = *(const bfrag*)(((const char*)&Ash[BUF][1][0]) + oaf[f_]); \
        bh[f_] = *(const bfrag*)(((const char*)&Wsh[BUF][0][0]) + obf[f_]); \
        bl[f_] = *(const bfrag*)(((const char*)&Wsh[BUF][1][0]) + obf[f_]); \
    } \
    _Pragma("unroll") \
    for (int mf_ = 0; mf_ < 4; ++mf_) \
        _Pragma("unroll") \
        for (int nf_ = 0; nf_ < 4; ++nf_) { \
            acc[mf_][nf_] = __builtin_amdgcn_mfma_f32_16x16x32_bf16(ah[mf_], bh[nf_], acc[mf_][nf_], 0, 0, 0); \
            acc[mf_][nf_] = __builtin_amdgcn_mfma_f32_16x16x32_bf16(ah[mf_], bl[nf_], acc[mf_][nf_], 0, 0, 0); \
            acc[mf_][nf_] = __builtin_amdgcn_mfma_f32_16x16x32_bf16(al[mf_], bh[nf_], acc[mf_][nf_], 0, 0, 0); \
        } } while (0)

__device__ __forceinline__ void gemm_body(
    const u16* __restrict__ Ah, const u16* __restrict__ Al,
    const u16* __restrict__ Wh, const u16* __restrict__ Wl,
    const float* __restrict__ bias, float oscale,
    float* __restrict__ Cf, u16* __restrict__ Chi, u16* __restrict__ Clo,
    int trans, int M, int N, int m0, int n0,
    u16 (*Ash)[2][4096], u16 (*Wsh)[2][4096])
{
    const int tid = threadIdx.x;
    const int w = tid >> 6, lane = tid & 63, lr = lane & 15, lg = lane >> 4;
    const int wm = w >> 1, wn = w & 1;

    // hoisted fragment addresses (byte offsets in an 8KB tile)
    int oaf[4], obf[4];
    #pragma unroll
    for (int f = 0; f < 4; ++f) {
        int ra = wm * 64 + f * 16 + lr;
        oaf[f] = ra * 64 + ((lg ^ ((ra >> 1) & 3)) * 16);
        int rb = wn * 64 + f * 16 + lr;
        obf[f] = rb * 64 + ((lg ^ ((rb >> 1) & 3)) * 16);
    }

    ffrag4 acc[4][4];
    #pragma unroll
    for (int i = 0; i < 4; ++i)
        #pragma unroll
        for (int j = 0; j < 4; ++j) acc[i][j] = (ffrag4)(0.0f);

    GSTAGE(0, 0);
    asm volatile("s_waitcnt vmcnt(0)" ::: "memory");
    __syncthreads();

    #pragma unroll 1
    for (int k0 = 0; k0 < DM; k0 += 64) {
        GSTAGE(1, k0 + 32);
        GCOMPUTE(0);
        asm volatile("s_waitcnt vmcnt(0)" ::: "memory");
        __syncthreads();
        if (k0 + 64 < DM) GSTAGE(0, k0 + 64);
        GCOMPUTE(1);
        asm volatile("s_waitcnt vmcnt(0)" ::: "memory");
        __syncthreads();
    }

    float bv[4] = {0.f, 0.f, 0.f, 0.f};
    if (bias) {
        #pragma unroll
        for (int nf = 0; nf < 4; ++nf) bv[nf] = bias[n0 + wn * 64 + nf * 16 + lr];
    }
    #pragma unroll
    for (int mf = 0; mf < 4; ++mf)
        #pragma unroll
        for (int nf = 0; nf < 4; ++nf)
            #pragma unroll
            for (int r = 0; r < 4; ++r) {
                int row = m0 + wm * 64 + mf * 16 + lg * 4 + r;
                int col = n0 + wn * 64 + nf * 16 + lr;
                float v = (acc[mf][nf][r] + bv[nf]) * oscale;
                if (Cf) Cf[(size_t)row * N + col] = v;
                if (Chi) {
                    u16 hh = f2bf(v), ll = f2bf(v - bf2f(hh));
                    size_t idx = trans ? ((size_t)col * M + row) : ((size_t)row * N + col);
                    Chi[idx] = hh; Clo[idx] = ll;
                }
            }
}

// out-projection (fp32 out)
__global__ __launch_bounds__(256) void gemm_out(
    const u16* __restrict__ Ah, const u16* __restrict__ Al,
    const u16* __restrict__ Wh, const u16* __restrict__ Wl,
    float* __restrict__ Cf)
{
    __shared__ u16 Ash[2][2][4096];
    __shared__ u16 Wsh[2][2][4096];
    gemm_body(Ah, Al, Wh, Wl, nullptr, 1.0f, Cf, nullptr, nullptr, 0, TLEN, DM,
              blockIdx.x * 128, blockIdx.y * 128, Ash, Wsh);
}

// fused Q/K/V projections: grid (32, 24); mat = by>>3. Q gets oscale=scaling.
struct QkvPtrs {
    const u16* Wh[3]; const u16* Wl[3]; const float* b[3];
    u16* Ch[3]; u16* Cl[3]; float sc[3];
};
__global__ __launch_bounds__(256, 3) void gemm_qkv(
    const u16* __restrict__ Ah, const u16* __restrict__ Al, QkvPtrs P)
{
    __shared__ u16 Ash[2][2][4096];
    __shared__ u16 Wsh[2][2][4096];
    const int mat = blockIdx.y >> 3;
    const int n0 = (blockIdx.y & 7) * 128;
    gemm_body(Ah, Al, P.Wh[mat], P.Wl[mat], P.b[mat], P.sc[mat],
              nullptr, P.Ch[mat], P.Cl[mat], (mat == 2) ? 1 : 0, TLEN, DM,
              blockIdx.x * 128, n0, Ash, Wsh);
}

// ---------------- fused attention: 8-wave K-split, swapped 32x32 MFMA ----------------
// Q is PRE-SCALED (scaling folded in at projection). gist-exp trimmed to fma+cvt
// (clamps provably dead: x<=~0 so y<=B<D; y<2^23 needs x<-87 -> impossible, and
// would yield a denormal ~0 == reference's 0 anyway). m folded into gist constant:
// Bp = fma(A, -m, B); e = bitcast(int(fma(A, s, Bp))).
#define P1_STAGE(BUF, J) \
    GLD16(kh_ + (size_t)((J) + srow) * DM + hc + ssl * 8, (char*)SM + (BUF) * 8192 + so)

#define P1_COMPUTE(BUF) do { \
    ffrag16 sfv = (ffrag16)(0.0f); \
    _Pragma("unroll") \
    for (int kd_ = 0; kd_ < 4; ++kd_) { \
        bfrag kf = *(const bfrag*)(SM + (BUF) * 8192 + kro + okd[kd_]); \
        sfv = __builtin_amdgcn_mfma_f32_32x32x16_bf16(kf, qhf[kd_], sfv, 0, 0, 0); \
    } \
    _Pragma("unroll") \
    for (int r_ = 0; r_ < 16; ++r_) rmax = fmaxf(rmax, sfv[r_]); } while (0)

#define P2_STAGE(BUF, J) do { \
    const size_t ko_ = (size_t)((J) + srow) * DM + hc + ssl * 8; \
    const size_t vo_ = (size_t)(hc + srow) * TLEN + (J) + ssl * 8; \
    GLD16(kh_ + ko_, (char*)SM + (0 + (BUF)) * 8192 + so); \
    GLD16(kl_ + ko_, (char*)SM + (2 + (BUF)) * 8192 + so); \
    GLD16(vth_ + vo_, (char*)SM + (4 + (BUF)) * 8192 + so); \
    GLD16(vtl_ + vo_, (char*)SM + (6 + (BUF)) * 8192 + so); } while (0)

#define P2_COMPUTE(BUF) do { \
    ffrag16 sfv = (ffrag16)(0.0f); \
    _Pragma("unroll") \
    for (int kd_ = 0; kd_ < 4; ++kd_) { \
        bfrag kf = *(const bfrag*)(SM + (BUF) * 8192 + kro + okd[kd_]); \
        bfrag lf = *(const bfrag*)(SM + (BUF) * 8192 + 16384 + kro + okd[kd_]); \
        sfv = __builtin_amdgcn_mfma_f32_32x32x16_bf16(kf, qhf[kd_], sfv, 0, 0, 0); \
        sfv = __builtin_amdgcn_mfma_f32_32x32x16_bf16(lf, qhf[kd_], sfv, 0, 0, 0); \
        sfv = __builtin_amdgcn_mfma_f32_32x32x16_bf16(kf, qlf[kd_], sfv, 0, 0, 0); \
    } \
    _Pragma("unroll") \
    for (int kt_ = 0; kt_ < 2; ++kt_) { \
        u32 hw_[2][2], lw_[2][2]; \
        _Pragma("unroll") \
        for (int gg_ = 0; gg_ < 2; ++gg_) \
            _Pragma("unroll") \
            for (int d2_ = 0; d2_ < 2; ++d2_) { \
                int ix_ = (kt_ * 2 + gg_) * 4 + d2_ * 2; \
                float y0_ = fmaf(12102203.17133801f, sfv[ix_ + 0], Bp); \
                float y1_ = fmaf(12102203.17133801f, sfv[ix_ + 1], Bp); \
                float e0_ = __int_as_float((int)y0_); \
                float e1_ = __int_as_float((int)y1_); \
                se0 += e0_; se1 += e1_; \
                __hip_bfloat162 hb_ = __float22bfloat162_rn(make_float2(e0_, e1_)); \
                u32 hwv_; memcpy(&hwv_, &hb_, 4); \
                float r0_ = e0_ - __uint_as_float(hwv_ << 16); \
                float r1_ = e1_ - __uint_as_float(hwv_ & 0xffff0000u); \
                __hip_bfloat162 lb_ = __float22bfloat162_rn(make_float2(r0_, r1_)); \
                u32 lwv_; memcpy(&lwv_, &lb_, 4); \
                hw_[gg_][d2_] = hwv_; lw_[gg_][d2_] = lwv_; \
            } \
        u32 a0_ = hw_[0][0], b0_ = hw_[1][0], a1_ = hw_[0][1], b1_ = hw_[1][1]; \
        asm volatile("v_permlane32_swap_b32 %0, %1" : "+v"(a0_), "+v"(b0_)); \
        asm volatile("v_permlane32_swap_b32 %0, %1" : "+v"(a1_), "+v"(b1_)); \
        u32 c0_ = lw_[0][0], d0_ = lw_[1][0], c1_ = lw_[0][1], d1_ = lw_[1][1]; \
        asm volatile("v_permlane32_swap_b32 %0, %1" : "+v"(c0_), "+v"(d0_)); \
        asm volatile("v_permlane32_swap_b32 %0, %1" : "+v"(c1_), "+v"(d1_)); \
        union { u32 u[4]; bfrag f; } ph_, pl_; \
        ph_.u[0] = a0_; ph_.u[1] = a1_; ph_.u[2] = b0_; ph_.u[3] = b1_; \
        pl_.u[0] = c0_; pl_.u[1] = c1_; pl_.u[2] = d0_; pl_.u[3] = d1_; \
        _Pragma("unroll") \
        for (int Fd_ = 0; Fd_ < 2; ++Fd_) { \
            bfrag vh_ = *(const bfrag*)(SM + (4 + (BUF)) * 8192 + vro[Fd_] + ovk[kt_]); \
            bfrag vl_ = *(const bfrag*)(SM + (4 + (BUF)) * 8192 + 16384 + vro[Fd_] + ovk[kt_]); \
            oac[Fd_] = __builtin_amdgcn_mfma_f32_32x32x16_bf16(vh_, ph_.f, oac[Fd_], 0, 0, 0); \
            oac[Fd_] = __builtin_amdgcn_mfma_f32_32x32x16_bf16(vl_, ph_.f, oac[Fd_], 0, 0, 0); \
            oac[Fd_] = __builtin_amdgcn_mfma_f32_32x32x16_bf16(vh_, pl_.f, oac[Fd_], 0, 0, 0); \
        } \
    } } while (0)

__global__ __launch_bounds__(512, 4) void attn_mfma(
    const u16* __restrict__ qh_, const u16* __restrict__ ql_,
    const u16* __restrict__ kh_, const u16* __restrict__ kl_,
    const u16* __restrict__ vth_, const u16* __restrict__ vtl_,   // [DM][TLEN]
    u16* __restrict__ oh_, u16* __restrict__ ol_)
{
    // [0..1]=KH bufs, [2..3]=KL, [4..5]=VH, [6..7]=VL (8KB each, 64KB total)
    __shared__ u16 SMEM[8][4096];
    const char* SM = (const char*)&SMEM[0][0];

    const int tid = threadIdx.x;
    const int w = tid >> 6, lane = tid & 63;
    const int q32 = lane & 31, h = lane >> 5;
    const int wq = w & 3, wg = w >> 2;
    const int t0 = blockIdx.x * 128, hc = blockIdx.y * HD;
    const int qrow = t0 + wq * 32 + q32;

    const int srow = tid >> 3;                 // staging row 0..63
    const int ssl  = (tid & 7) ^ (srow & 7);   // swizzled 16B slot
    const int so   = tid * 16;

    // hoisted LDS fragment geometry
    const int c = q32 & 7;
    const int kro = (wg * 32 + q32) * 128;
    int okd[4], ovk[2], vro[2];
    #pragma unroll
    for (int kd = 0; kd < 4; ++kd) okd[kd] = ((kd * 2 + h) ^ c) * 16;
    #pragma unroll
    for (int kt = 0; kt < 2; ++kt) ovk[kt] = ((wg * 4 + kt * 2 + h) ^ c) * 16;
    vro[0] = q32 * 128; vro[1] = (32 + q32) * 128;

    // Q fragments (B-side: col=q32, k = kd*16 + h*8 + e); q pre-scaled
    bfrag qhf[4], qlf[4];
    {
        const size_t qo = (size_t)qrow * DM + hc + h * 8;
        #pragma unroll
        for (int kd = 0; kd < 4; ++kd) {
            qhf[kd] = *(const bfrag*)&qh_[qo + kd * 16];
            qlf[kd] = *(const bfrag*)&ql_[qo + kd * 16];
        }
    }

    // ---- pass 1: per-q-row max of hi-only (pre-scaled) scores, this wave's key half ----
    float rmax = -3.402823466e38f;
    P1_STAGE(0, 0);
    asm volatile("s_waitcnt vmcnt(0)" ::: "memory");
    __syncthreads();
    #pragma unroll 1
    for (int j0 = 0; j0 < TLEN; j0 += 128) {
        P1_STAGE(1, j0 + 64);
        P1_COMPUTE(0);
        asm volatile("s_waitcnt vmcnt(0)" ::: "memory");
        __syncthreads();
        if (j0 + 128 < TLEN) P1_STAGE(0, j0 + 128);
        P1_COMPUTE(1);
        asm volatile("s_waitcnt vmcnt(0)" ::: "memory");
        __syncthreads();
    }
    rmax = fmaxf(rmax, __shfl_xor(rmax, 32, 64));

    // combine max across the wg pair via SMEM[7] scratch
    {
        float* MxA = (float*)&SMEM[7][0];
        float* MxB = MxA + 128;
        if (wg == 1 && lane < 32) MxA[wq * 32 + q32] = rmax;
        __syncthreads();
        if (wg == 0) {
            rmax = fmaxf(rmax, MxA[wq * 32 + q32]);
            if (lane < 32) MxB[wq * 32 + q32] = rmax;
        }
        __syncthreads();
        rmax = MxB[wq * 32 + q32];
    }
    const float Bp = fmaf(12102203.17133801f, -rmax, 1064986823.010288f);

    // ---- pass 2 ----
    ffrag16 oac[2];
    oac[0] = (ffrag16)(0.0f); oac[1] = (ffrag16)(0.0f);
    float se0 = 0.0f, se1 = 0.0f;

    P2_STAGE(0, 0);
    asm volatile("s_waitcnt vmcnt(0)" ::: "memory");
    __syncthreads();
    #pragma unroll 1
    for (int j0 = 0; j0 < TLEN; j0 += 128) {
        P2_STAGE(1, j0 + 64);
        P2_COMPUTE(0);
        asm volatile("s_waitcnt vmcnt(0)" ::: "memory");
        __syncthreads();
        if (j0 + 128 < TLEN) P2_STAGE(0, j0 + 128);
        P2_COMPUTE(1);
        asm volatile("s_waitcnt vmcnt(0)" ::: "memory");
        __syncthreads();
    }

    float se = se0 + se1;
    se += __shfl_xor(se, 32, 64);

    // ---- combine wave-pair partials (exact fp32 adds; shared global max) ----
    float* S = (float*)&SMEM[0][0];
    if (wg == 1) {
        #pragma unroll
        for (int Fd = 0; Fd < 2; ++Fd)
            #pragma unroll
            for (int r = 0; r < 16; ++r)
                S[((wq * 32 + Fd * 16 + r) * 64) + lane] = oac[Fd][r];
        S[8192 + wq * 64 + lane] = se;
    }
    __syncthreads();
    if (wg == 0) {
        se += S[8192 + wq * 64 + lane];
        const float inv = 1.0f / se;
        #pragma unroll
        for (int Fd = 0; Fd < 2; ++Fd)
            #pragma unroll
            for (int Rq = 0; Rq < 4; ++Rq) {
                ushort4 hv, lv;
                #pragma unroll
                for (int m = 0; m < 4; ++m) {
                    float v = (oac[Fd][Rq * 4 + m] +
                               S[((wq * 32 + Fd * 16 + Rq * 4 + m) * 64) + lane]) * inv;
                    u16 hh = f2bf(v);
                    ((u16*)&hv)[m] = hh;
                    ((u16*)&lv)[m] = f2bf(v - bf2f(hh));
                }
                size_t off = (size_t)qrow * DM + hc + Fd * 32 + Rq * 8 + h * 4;
                *(ushort4*)&oh_[off] = hv;
                *(ushort4*)&ol_[off] = lv;
            }
    }
}

extern "C" void kernel_launch(void* const* d_in, const int* in_sizes, int n_in,
                              void* d_out, int out_size, void* d_ws, size_t ws_size,
                              hipStream_t stream)
{
    const float* x  = (const float*)d_in[0];
    const float* Wq = (const float*)d_in[1];
    const float* bq = (const float*)d_in[2];
    const float* Wk = (const float*)d_in[3];
    const float* bk = (const float*)d_in[4];
    const float* Wv = (const float*)d_in[5];
    const float* bv = (const float*)d_in[6];
    const float* Wo = (const float*)d_in[7];
    float* out = (float*)d_out;

    // workspace layout (bf16 halves), 80 MB total
    u16* p = (u16*)d_ws;
    u16* xh  = p; p += (size_t)TLEN * DM;
    u16* xl  = p; p += (size_t)TLEN * DM;
    u16* wqh = p; p += (size_t)DM * DM;  u16* wql = p; p += (size_t)DM * DM;
    u16* wkh = p; p += (size_t)DM * DM;  u16* wkl = p; p += (size_t)DM * DM;
    u16* wvh = p; p += (size_t)DM * DM;  u16* wvl = p; p += (size_t)DM * DM;
    u16* woh = p; p += (size_t)DM * DM;  u16* wol = p; p += (size_t)DM * DM;
    u16* qh  = p; p += (size_t)TLEN * DM;  u16* ql  = p; p += (size_t)TLEN * DM;
    u16* kh  = p; p += (size_t)TLEN * DM;  u16* kl  = p; p += (size_t)TLEN * DM;
    u16* vth = p; p += (size_t)TLEN * DM;  u16* vtl = p; p += (size_t)TLEN * DM;
    u16* oh = xh;  u16* ol = xl;   // x fully consumed before attn writes o

    // Quake fast-rsqrt(HEAD_DIM), bit-exact vs reference (host-side)
    float hx = (float)HD;
    int bi; memcpy(&bi, &hx, 4);
    bi = (int)(0x5F3759DFLL - ((long long)bi >> 1));
    float yy; memcpy(&yy, &bi, 4);
    float scaling = yy * (1.5f - 0.5f * hx * yy * yy);

    split_x<<<4096, 256, 0, stream>>>(x, xh, xl);
    SplitPtrs SP;
    SP.src[0] = Wq; SP.src[1] = Wk; SP.src[2] = Wv; SP.src[3] = Wo;
    SP.hi[0] = wqh; SP.hi[1] = wkh; SP.hi[2] = wvh; SP.hi[3] = woh;
    SP.lo[0] = wql; SP.lo[1] = wkl; SP.lo[2] = wvl; SP.lo[3] = wol;
    split_w<<<dim3(1024, 4), 256, 0, stream>>>(SP);

    QkvPtrs QP;
    QP.Wh[0] = wqh; QP.Wh[1] = wkh; QP.Wh[2] = wvh;
    QP.Wl[0] = wql; QP.Wl[1] = wkl; QP.Wl[2] = wvl;
    QP.b[0] = bq; QP.b[1] = bk; QP.b[2] = bv;
    QP.Ch[0] = qh; QP.Ch[1] = kh; QP.Ch[2] = vth;
    QP.Cl[0] = ql; QP.Cl[1] = kl; QP.Cl[2] = vtl;
    QP.sc[0] = scaling; QP.sc[1] = 1.0f; QP.sc[2] = 1.0f;   // fold scaling into Q
    gemm_qkv<<<dim3(TLEN / 128, 24), 256, 0, stream>>>(xh, xl, QP);

    attn_mfma<<<dim3(TLEN / 128, NHEAD), 512, 0, stream>>>(qh, ql, kh, kl, vth, vtl, oh, ol);

    gemm_out<<<dim3(TLEN / 128, DM / 128), 256, 0, stream>>>(oh, ol, woh, wol, out);
}

// Round 7
// 332.029 us; speedup vs baseline: 7.6601x; 1.3909x over previous
//
#include <hip/hip_runtime.h>
#include <hip/hip_bf16.h>
#include <cstring>

typedef unsigned short u16;
typedef unsigned int   u32;
typedef __attribute__((ext_vector_type(8)))  short bfrag;    // 8 bf16 = 4 VGPR
typedef __attribute__((ext_vector_type(4)))  float ffrag4;   // 16x16 acc
typedef __attribute__((ext_vector_type(16))) float ffrag16;  // 32x32 acc

#define TLEN 4096
#define DM   1024
#define NHEAD 16
#define HD    64

__device__ __forceinline__ u16 f2bf(float f) {
    u32 u = __float_as_uint(f);
    u32 r = (u + 0x7FFFu + ((u >> 16) & 1u)) >> 16;
    return (u16)r;
}
__device__ __forceinline__ float bf2f(u16 h) { return __uint_as_float(((u32)h) << 16); }

#define GLD16(gsrc, ldst) \
  __builtin_amdgcn_global_load_lds((const __attribute__((address_space(1))) u32*)(gsrc), \
                                   (__attribute__((address_space(3))) u32*)(ldst), 16, 0, 0)

// ---------------- split fp32 -> (hi, lo) bf16 ----------------
__global__ __launch_bounds__(256) void split_x(const float* __restrict__ a,
                                               u16* __restrict__ hi, u16* __restrict__ lo) {
    int i = (blockIdx.x * 256 + threadIdx.x) * 4;
    float4 v = *(const float4*)&a[i];
    u16 h0 = f2bf(v.x), h1 = f2bf(v.y), h2 = f2bf(v.z), h3 = f2bf(v.w);
    ushort4 hv; hv.x = h0; hv.y = h1; hv.z = h2; hv.w = h3;
    ushort4 lv;
    lv.x = f2bf(v.x - bf2f(h0)); lv.y = f2bf(v.y - bf2f(h1));
    lv.z = f2bf(v.z - bf2f(h2)); lv.w = f2bf(v.w - bf2f(h3));
    *(ushort4*)&hi[i] = hv;
    *(ushort4*)&lo[i] = lv;
}

struct SplitPtrs { const float* src[4]; u16* hi[4]; u16* lo[4]; };
__global__ __launch_bounds__(256) void split_w(SplitPtrs P) {
    int m = blockIdx.y;
    int i = (blockIdx.x * 256 + threadIdx.x) * 4;
    float4 v = *(const float4*)&P.src[m][i];
    u16 h0 = f2bf(v.x), h1 = f2bf(v.y), h2 = f2bf(v.z), h3 = f2bf(v.w);
    ushort4 hv; hv.x = h0; hv.y = h1; hv.z = h2; hv.w = h3;
    ushort4 lv;
    lv.x = f2bf(v.x - bf2f(h0)); lv.y = f2bf(v.y - bf2f(h1));
    lv.z = f2bf(v.z - bf2f(h2)); lv.w = f2bf(v.w - bf2f(h3));
    *(ushort4*)&P.hi[m][i] = hv;
    *(ushort4*)&P.lo[m][i] = lv;
}

// ---------------- bf16x3 GEMM body (64x128 tile, BK=32, 4 waves, unroll-2) ----------------
// C = A[M][1024] * W[N][1024]^T (+bias). Wave w: rows m0..m0+63, cols n0+w*32..+32.
#define GSTAGE(BUF, K0) do { \
    { int o_ = tid * 16; \
      int row_ = o_ >> 6; \
      int sl_ = ((o_ >> 4) & 3) ^ ((row_ >> 1) & 3); \
      const size_t ga_ = (size_t)(m0 + row_) * DM + (K0) + sl_ * 8; \
      GLD16(Ah + ga_, ((char*)&Ash[BUF][0][0]) + o_); \
      GLD16(Al + ga_, ((char*)&Ash[BUF][1][0]) + o_); } \
    _Pragma("unroll") \
    for (int i_ = 0; i_ < 2; ++i_) { \
        int o_ = (i_ * 256 + tid) * 16; \
        int row_ = o_ >> 6; \
        int sl_ = ((o_ >> 4) & 3) ^ ((row_ >> 1) & 3); \
        const size_t gw_ = (size_t)(n0 + row_) * DM + (K0) + sl_ * 8; \
        GLD16(Wh + gw_, ((char*)&Wsh[BUF][0][0]) + o_); \
        GLD16(Wl + gw_, ((char*)&Wsh[BUF][1][0]) + o_); \
    } } while (0)

#define GCOMPUTE(BUF) do { \
    bfrag ah[4], al[4], bh[2], bl[2]; \
    _Pragma("unroll") \
    for (int f_ = 0; f_ < 4; ++f_) { \
        ah[f_] = *(const bfrag*)(((const char*)&Ash[BUF][0][0]) + oaf[f_]); \
        al[f_] = *(const bfrag*)(((const char*)&Ash[BUF][1][0]) + oaf[f_]); \
    } \
    _Pragma("unroll") \
    for (int f_ = 0; f_ < 2; ++f_) { \
        bh[f_] = *(const bfrag*)(((const char*)&Wsh[BUF][0][0]) + obf[f_]); \
        bl[f_] = *(const bfrag*)(((const char*)&Wsh[BUF][1][0]) + obf[f_]); \
    } \
    _Pragma("unroll") \
    for (int mf_ = 0; mf_ < 4; ++mf_) \
        _Pragma("unroll") \
        for (int nf_ = 0; nf_ < 2; ++nf_) { \
            acc[mf_][nf_] = __builtin_amdgcn_mfma_f32_16x16x32_bf16(ah[mf_], bh[nf_], acc[mf_][nf_], 0, 0, 0); \
            acc[mf_][nf_] = __builtin_amdgcn_mfma_f32_16x16x32_bf16(ah[mf_], bl[nf_], acc[mf_][nf_], 0, 0, 0); \
            acc[mf_][nf_] = __builtin_amdgcn_mfma_f32_16x16x32_bf16(al[mf_], bh[nf_], acc[mf_][nf_], 0, 0, 0); \
        } } while (0)

__device__ __forceinline__ void gemm_body(
    const u16* __restrict__ Ah, const u16* __restrict__ Al,
    const u16* __restrict__ Wh, const u16* __restrict__ Wl,
    const float* __restrict__ bias, float oscale,
    float* __restrict__ Cf, u16* __restrict__ Chi, u16* __restrict__ Clo,
    int trans, int M, int N, int m0, int n0,
    u16 (*Ash)[2][2048], u16 (*Wsh)[2][4096])
{
    const int tid = threadIdx.x;
    const int w = tid >> 6, lane = tid & 63, lr = lane & 15, lg = lane >> 4;

    // hoisted fragment byte offsets
    int oaf[4], obf[2];
    #pragma unroll
    for (int f = 0; f < 4; ++f) {
        int ra = f * 16 + lr;
        oaf[f] = ra * 64 + ((lg ^ ((ra >> 1) & 3)) * 16);
    }
    #pragma unroll
    for (int f = 0; f < 2; ++f) {
        int rb = w * 32 + f * 16 + lr;
        obf[f] = rb * 64 + ((lg ^ ((rb >> 1) & 3)) * 16);
    }

    ffrag4 acc[4][2];
    #pragma unroll
    for (int i = 0; i < 4; ++i)
        #pragma unroll
        for (int j = 0; j < 2; ++j) acc[i][j] = (ffrag4)(0.0f);

    GSTAGE(0, 0);
    asm volatile("s_waitcnt vmcnt(0)" ::: "memory");
    __syncthreads();

    #pragma unroll 1
    for (int k0 = 0; k0 < DM; k0 += 64) {
        GSTAGE(1, k0 + 32);
        GCOMPUTE(0);
        asm volatile("s_waitcnt vmcnt(0)" ::: "memory");
        __syncthreads();
        if (k0 + 64 < DM) GSTAGE(0, k0 + 64);
        GCOMPUTE(1);
        asm volatile("s_waitcnt vmcnt(0)" ::: "memory");
        __syncthreads();
    }

    float bv[2] = {0.f, 0.f};
    if (bias) {
        #pragma unroll
        for (int nf = 0; nf < 2; ++nf) bv[nf] = bias[n0 + w * 32 + nf * 16 + lr];
    }
    #pragma unroll
    for (int mf = 0; mf < 4; ++mf)
        #pragma unroll
        for (int nf = 0; nf < 2; ++nf)
            #pragma unroll
            for (int r = 0; r < 4; ++r) {
                int row = m0 + mf * 16 + lg * 4 + r;
                int col = n0 + w * 32 + nf * 16 + lr;
                float v = (acc[mf][nf][r] + bv[nf]) * oscale;
                if (Cf) Cf[(size_t)row * N + col] = v;
                if (Chi) {
                    u16 hh = f2bf(v);
                    size_t idx = trans ? ((size_t)col * M + row) : ((size_t)row * N + col);
                    Chi[idx] = hh;
                    if (Clo) Clo[idx] = f2bf(v - bf2f(hh));
                }
            }
}

// out-projection (fp32 out)
__global__ __launch_bounds__(256, 3) void gemm_out(
    const u16* __restrict__ Ah, const u16* __restrict__ Al,
    const u16* __restrict__ Wh, const u16* __restrict__ Wl,
    float* __restrict__ Cf)
{
    __shared__ u16 Ash[2][2][2048];
    __shared__ u16 Wsh[2][2][4096];
    gemm_body(Ah, Al, Wh, Wl, nullptr, 1.0f, Cf, nullptr, nullptr, 0, TLEN, DM,
              blockIdx.x * 64, blockIdx.y * 128, Ash, Wsh);
}

// fused Q/K/V projections: grid (64, 24); mat = by>>3. Q gets oscale=scaling.
// hi-only outputs (attention internals are bf16).
struct QkvPtrs {
    const u16* Wh[3]; const u16* Wl[3]; const float* b[3];
    u16* Ch[3]; float sc[3];
};
__global__ __launch_bounds__(256, 3) void gemm_qkv(
    const u16* __restrict__ Ah, const u16* __restrict__ Al, QkvPtrs P)
{
    __shared__ u16 Ash[2][2][2048];
    __shared__ u16 Wsh[2][2][4096];
    const int mat = blockIdx.y >> 3;
    const int n0 = (blockIdx.y & 7) * 128;
    gemm_body(Ah, Al, P.Wh[mat], P.Wl[mat], P.b[mat], P.sc[mat],
              nullptr, P.Ch[mat], nullptr, (mat == 2) ? 1 : 0, TLEN, DM,
              blockIdx.x * 64, n0, Ash, Wsh);
}

// ---------------- fused attention: 8-wave K-split, hi-only bf16, swapped 32x32 ----------------
// Pass-1 max and pass-2 scores are the SAME MFMAs on the same fragments -> bit-identical,
// so s - m <= 0 exactly; gist clamps provably dead (see R6 note). Bp folds m.
#define P1_STAGE(BUF, J) \
    GLD16(kh_ + (size_t)((J) + srow) * DM + hc + ssl * 8, (char*)SM + (BUF) * 8192 + so)

#define P1_COMPUTE(BUF) do { \
    ffrag16 sfv = (ffrag16)(0.0f); \
    _Pragma("unroll") \
    for (int kd_ = 0; kd_ < 4; ++kd_) { \
        bfrag kf = *(const bfrag*)(SM + (BUF) * 8192 + kro + okd[kd_]); \
        sfv = __builtin_amdgcn_mfma_f32_32x32x16_bf16(kf, qhf[kd_], sfv, 0, 0, 0); \
    } \
    _Pragma("unroll") \
    for (int r_ = 0; r_ < 16; ++r_) rmax = fmaxf(rmax, sfv[r_]); } while (0)

#define P2_STAGE(BUF, J) do { \
    const size_t ko_ = (size_t)((J) + srow) * DM + hc + ssl * 8; \
    const size_t vo_ = (size_t)(hc + srow) * TLEN + (J) + ssl * 8; \
    GLD16(kh_ + ko_, (char*)SM + (0 + (BUF)) * 8192 + so); \
    GLD16(vth_ + vo_, (char*)SM + (2 + (BUF)) * 8192 + so); } while (0)

#define P2_COMPUTE(BUF) do { \
    ffrag16 sfv = (ffrag16)(0.0f); \
    _Pragma("unroll") \
    for (int kd_ = 0; kd_ < 4; ++kd_) { \
        bfrag kf = *(const bfrag*)(SM + (BUF) * 8192 + kro + okd[kd_]); \
        sfv = __builtin_amdgcn_mfma_f32_32x32x16_bf16(kf, qhf[kd_], sfv, 0, 0, 0); \
    } \
    _Pragma("unroll") \
    for (int kt_ = 0; kt_ < 2; ++kt_) { \
        u32 hw_[2][2]; \
        _Pragma("unroll") \
        for (int gg_ = 0; gg_ < 2; ++gg_) \
            _Pragma("unroll") \
            for (int d2_ = 0; d2_ < 2; ++d2_) { \
                int ix_ = (kt_ * 2 + gg_) * 4 + d2_ * 2; \
                float y0_ = fmaf(12102203.17133801f, sfv[ix_ + 0], Bp); \
                float y1_ = fmaf(12102203.17133801f, sfv[ix_ + 1], Bp); \
                float e0_ = __int_as_float((int)y0_); \
                float e1_ = __int_as_float((int)y1_); \
                se0 += e0_; se1 += e1_; \
                __hip_bfloat162 hb_ = __float22bfloat162_rn(make_float2(e0_, e1_)); \
                u32 hwv_; memcpy(&hwv_, &hb_, 4); \
                hw_[gg_][d2_] = hwv_; \
            } \
        u32 a0_ = hw_[0][0], b0_ = hw_[1][0], a1_ = hw_[0][1], b1_ = hw_[1][1]; \
        asm volatile("v_permlane32_swap_b32 %0, %1" : "+v"(a0_), "+v"(b0_)); \
        asm volatile("v_permlane32_swap_b32 %0, %1" : "+v"(a1_), "+v"(b1_)); \
        union { u32 u[4]; bfrag f; } ph_; \
        ph_.u[0] = a0_; ph_.u[1] = a1_; ph_.u[2] = b0_; ph_.u[3] = b1_; \
        _Pragma("unroll") \
        for (int Fd_ = 0; Fd_ < 2; ++Fd_) { \
            bfrag vh_ = *(const bfrag*)(SM + (2 + (BUF)) * 8192 + vro[Fd_] + ovk[kt_]); \
            oac[Fd_] = __builtin_amdgcn_mfma_f32_32x32x16_bf16(vh_, ph_.f, oac[Fd_], 0, 0, 0); \
        } \
    } } while (0)

__global__ __launch_bounds__(512, 4) void attn_mfma(
    const u16* __restrict__ qh_, const u16* __restrict__ kh_,
    const u16* __restrict__ vth_,                         // [DM][TLEN]
    u16* __restrict__ oh_, u16* __restrict__ ol_)
{
    // [0..1] = K bufs, [2..3] = V bufs, [4] = reduce scratch (40KB total)
    __shared__ u16 SMEM[5][4096];
    const char* SM = (const char*)&SMEM[0][0];

    const int tid = threadIdx.x;
    const int w = tid >> 6, lane = tid & 63;
    const int q32 = lane & 31, h = lane >> 5;
    const int wq = w & 3, wg = w >> 2;
    const int t0 = blockIdx.x * 128, hc = blockIdx.y * HD;
    const int qrow = t0 + wq * 32 + q32;

    const int srow = tid >> 3;                 // staging row 0..63
    const int ssl  = (tid & 7) ^ (srow & 7);   // swizzled 16B slot
    const int so   = tid * 16;

    // hoisted LDS fragment geometry
    const int c = q32 & 7;
    const int kro = (wg * 32 + q32) * 128;
    int okd[4], ovk[2], vro[2];
    #pragma unroll
    for (int kd = 0; kd < 4; ++kd) okd[kd] = ((kd * 2 + h) ^ c) * 16;
    #pragma unroll
    for (int kt = 0; kt < 2; ++kt) ovk[kt] = ((wg * 4 + kt * 2 + h) ^ c) * 16;
    vro[0] = q32 * 128; vro[1] = (32 + q32) * 128;

    // Q fragments (B-side: col=q32, k = kd*16 + h*8 + e); q pre-scaled, hi only
    bfrag qhf[4];
    {
        const size_t qo = (size_t)qrow * DM + hc + h * 8;
        #pragma unroll
        for (int kd = 0; kd < 4; ++kd) qhf[kd] = *(const bfrag*)&qh_[qo + kd * 16];
    }

    // ---- pass 1: per-q-row max over this wave's key half ----
    float rmax = -3.402823466e38f;
    P1_STAGE(0, 0);
    asm volatile("s_waitcnt vmcnt(0)" ::: "memory");
    __syncthreads();
    #pragma unroll 1
    for (int j0 = 0; j0 < TLEN; j0 += 128) {
        P1_STAGE(1, j0 + 64);
        P1_COMPUTE(0);
        asm volatile("s_waitcnt vmcnt(0)" ::: "memory");
        __syncthreads();
        if (j0 + 128 < TLEN) P1_STAGE(0, j0 + 128);
        P1_COMPUTE(1);
        asm volatile("s_waitcnt vmcnt(0)" ::: "memory");
        __syncthreads();
    }
    rmax = fmaxf(rmax, __shfl_xor(rmax, 32, 64));

    // combine max across the wg pair via SMEM[4]
    {
        float* MxA = (float*)&SMEM[4][0];
        float* MxB = MxA + 128;
        if (wg == 1 && lane < 32) MxA[wq * 32 + q32] = rmax;
        __syncthreads();
        if (wg == 0) {
            rmax = fmaxf(rmax, MxA[wq * 32 + q32]);
            if (lane < 32) MxB[wq * 32 + q32] = rmax;
        }
        __syncthreads();
        rmax = MxB[wq * 32 + q32];
    }
    const float Bp = fmaf(12102203.17133801f, -rmax, 1064986823.010288f);

    // ---- pass 2: scores (bit-identical MFMAs) -> gist -> permlane -> PV ----
    ffrag16 oac[2];
    oac[0] = (ffrag16)(0.0f); oac[1] = (ffrag16)(0.0f);
    float se0 = 0.0f, se1 = 0.0f;

    P2_STAGE(0, 0);
    asm volatile("s_waitcnt vmcnt(0)" ::: "memory");
    __syncthreads();
    #pragma unroll 1
    for (int j0 = 0; j0 < TLEN; j0 += 128) {
        P2_STAGE(1, j0 + 64);
        P2_COMPUTE(0);
        asm volatile("s_waitcnt vmcnt(0)" ::: "memory");
        __syncthreads();
        if (j0 + 128 < TLEN) P2_STAGE(0, j0 + 128);
        P2_COMPUTE(1);
        asm volatile("s_waitcnt vmcnt(0)" ::: "memory");
        __syncthreads();
    }

    float se = se0 + se1;
    se += __shfl_xor(se, 32, 64);

    // ---- combine wave-pair partials (exact fp32 adds; shared global max) ----
    float* S = (float*)&SMEM[0][0];   // 32KB oac partials + se at float idx 8192
    if (wg == 1) {
        #pragma unroll
        for (int Fd = 0; Fd < 2; ++Fd)
            #pragma unroll
            for (int r = 0; r < 16; ++r)
                S[((wq * 32 + Fd * 16 + r) * 64) + lane] = oac[Fd][r];
        S[8192 + wq * 64 + lane] = se;
    }
    __syncthreads();
    if (wg == 0) {
        se += S[8192 + wq * 64 + lane];
        const float inv = 1.0f / se;
        #pragma unroll
        for (int Fd = 0; Fd < 2; ++Fd)
            #pragma unroll
            for (int Rq = 0; Rq < 4; ++Rq) {
                ushort4 hv, lv;
                #pragma unroll
                for (int m = 0; m < 4; ++m) {
                    float v = (oac[Fd][Rq * 4 + m] +
                               S[((wq * 32 + Fd * 16 + Rq * 4 + m) * 64) + lane]) * inv;
                    u16 hh = f2bf(v);
                    ((u16*)&hv)[m] = hh;
                    ((u16*)&lv)[m] = f2bf(v - bf2f(hh));
                }
                size_t off = (size_t)qrow * DM + hc + Fd * 32 + Rq * 8 + h * 4;
                *(ushort4*)&oh_[off] = hv;
                *(ushort4*)&ol_[off] = lv;
            }
    }
}

extern "C" void kernel_launch(void* const* d_in, const int* in_sizes, int n_in,
                              void* d_out, int out_size, void* d_ws, size_t ws_size,
                              hipStream_t stream)
{
    const float* x  = (const float*)d_in[0];
    const float* Wq = (const float*)d_in[1];
    const float* bq = (const float*)d_in[2];
    const float* Wk = (const float*)d_in[3];
    const float* bk = (const float*)d_in[4];
    const float* Wv = (const float*)d_in[5];
    const float* bv = (const float*)d_in[6];
    const float* Wo = (const float*)d_in[7];
    float* out = (float*)d_out;

    // workspace layout (bf16), ~56 MB
    u16* p = (u16*)d_ws;
    u16* xh  = p; p += (size_t)TLEN * DM;
    u16* xl  = p; p += (size_t)TLEN * DM;
    u16* wqh = p; p += (size_t)DM * DM;  u16* wql = p; p += (size_t)DM * DM;
    u16* wkh = p; p += (size_t)DM * DM;  u16* wkl = p; p += (size_t)DM * DM;
    u16* wvh = p; p += (size_t)DM * DM;  u16* wvl = p; p += (size_t)DM * DM;
    u16* woh = p; p += (size_t)DM * DM;  u16* wol = p; p += (size_t)DM * DM;
    u16* qh  = p; p += (size_t)TLEN * DM;
    u16* kh  = p; p += (size_t)TLEN * DM;
    u16* vth = p; p += (size_t)TLEN * DM;
    u16* oh = xh;  u16* ol = xl;   // x fully consumed before attn writes o

    // Quake fast-rsqrt(HEAD_DIM), bit-exact vs reference (host-side)
    float hx = (float)HD;
    int bi; memcpy(&bi, &hx, 4);
    bi = (int)(0x5F3759DFLL - ((long long)bi >> 1));
    float yy; memcpy(&yy, &bi, 4);
    float scaling = yy * (1.5f - 0.5f * hx * yy * yy);

    split_x<<<4096, 256, 0, stream>>>(x, xh, xl);
    SplitPtrs SP;
    SP.src[0] = Wq; SP.src[1] = Wk; SP.src[2] = Wv; SP.src[3] = Wo;
    SP.hi[0] = wqh; SP.hi[1] = wkh; SP.hi[2] = wvh; SP.hi[3] = woh;
    SP.lo[0] = wql; SP.lo[1] = wkl; SP.lo[2] = wvl; SP.lo[3] = wol;
    split_w<<<dim3(1024, 4), 256, 0, stream>>>(SP);

    QkvPtrs QP;
    QP.Wh[0] = wqh; QP.Wh[1] = wkh; QP.Wh[2] = wvh;
    QP.Wl[0] = wql; QP.Wl[1] = wkl; QP.Wl[2] = wvl;
    QP.b[0] = bq; QP.b[1] = bk; QP.b[2] = bv;
    QP.Ch[0] = qh; QP.Ch[1] = kh; QP.Ch[2] = vth;
    QP.sc[0] = scaling; QP.sc[1] = 1.0f; QP.sc[2] = 1.0f;   // scaling folded into Q
    gemm_qkv<<<dim3(TLEN / 64, 24), 256, 0, stream>>>(xh, xl, QP);

    attn_mfma<<<dim3(TLEN / 128, NHEAD), 512, 0, stream>>>(qh, kh, vth, oh, ol);

    gemm_out<<<dim3(TLEN / 64, 8), 256, 0, stream>>>(oh, ol, woh, wol, out);
}